// Round 6
// baseline (11997.207 us; speedup 1.0000x reference)
//
#include <hip/hip_runtime.h>
#include <hip/hip_bf16.h>
#include <math.h>

// ---------------------------------------------------------------------------
// ROUND 6: full pipeline, all-fp32, FP32 OUTPUT (reference returns float32,
// harness doc: d_out has the reference's output dtype -> float*).
// Plain-C kernels, fresh names (_r6) to force rebuild (rounds 2-4 ran stale).
// Workspace layout identical to round 1's (151 MB peak, proven to execute).
// ---------------------------------------------------------------------------

// C[M,N] = A[M,K] @ W[K,N], fp32
__global__ __launch_bounds__(256) void msa_gemm_r6(
    const float* __restrict__ A, const float* __restrict__ W,
    float* __restrict__ C, int K, int N)
{
  const int row = blockIdx.x;
  const int col = blockIdx.y * 256 + threadIdx.x;
  if (col >= N) return;
  const float* a = A + (size_t)row * K;
  float acc = 0.f;
  for (int k = 0; k < K; ++k)
    acc = fmaf(a[k], W[(size_t)k * N + col], acc);
  C[(size_t)row * N + col] = acc;
}

// out[M,N] = A[M,K] @ W[K,N] + bias   (fp32 out)
__global__ __launch_bounds__(256) void msa_gemm_out_r6(
    const float* __restrict__ A, const float* __restrict__ W,
    const float* __restrict__ bias, float* __restrict__ C, int K, int N)
{
  const int row = blockIdx.x;
  const int col = blockIdx.y * 256 + threadIdx.x;
  if (col >= N) return;
  const float* a = A + (size_t)row * K;
  float acc = 0.f;
  for (int k = 0; k < K; ++k)
    acc = fmaf(a[k], W[(size_t)k * N + col], acc);
  C[(size_t)row * N + col] = acc + bias[col];
}

// attention, one thread per query row.
// mode 0: local windowed (PATCH-order output rows). mode 1: global 1024-token.
__global__ __launch_bounds__(64) void msa_attn_r6(
    const float* __restrict__ qsrc, const float* __restrict__ kvsrc,
    float* __restrict__ out, int head, int p, int mode)
{
  const int b = blockIdx.y;
  const int nq = blockIdx.x * 64 + threadIdx.x;
  const int NTOK = mode ? 1024 : 4096;
  const int P2 = mode ? 1024 : p * p;

  int n, hb = 0, wb = 0;
  if (mode) {
    n = nq;
  } else {
    const int patch = nq / P2;
    const int t = nq - patch * P2;
    const int nbp = 64 / p;
    hb = patch / nbp;
    wb = patch - hb * nbp;
    const int hp = t / p;
    const int wp = t - hp * p;
    n = (hb * p + hp) * 64 + (wb * p + wp);
  }

  const float* q = qsrc + ((size_t)b * NTOK + n) * 256 + head * 32;
  float qr[32];
  for (int c = 0; c < 32; ++c) qr[c] = q[c];

  const float scale = 0.17677669529663687f;  // 32^-0.5
  float m = -3.0e38f, l = 0.f;
  float acc[32];
  for (int c = 0; c < 32; ++c) acc[c] = 0.f;

  for (int kk = 0; kk < P2; ++kk) {
    int nk;
    if (mode) {
      nk = kk;
    } else {
      const int khp = kk / p;
      const int kwp = kk - khp * p;
      nk = (hb * p + khp) * 64 + (wb * p + kwp);
    }
    const float* kvp = kvsrc + ((size_t)b * NTOK + nk) * 512 + head * 32;
    float s = 0.f;
    for (int c = 0; c < 32; ++c) s = fmaf(qr[c], kvp[c], s);
    s *= scale;
    const float mnew = fmaxf(m, s);
    const float f  = __expf(m - mnew);
    const float pe = __expf(s - mnew);
    l = l * f + pe;
    for (int c = 0; c < 32; ++c)
      acc[c] = fmaf(acc[c], f, pe * kvp[256 + c]);
    m = mnew;
  }

  const float inv = 1.f / l;
  float* dst = out + ((size_t)b * NTOK + nq) * 256 + head * 32;
  for (int c = 0; c < 32; ++c) dst[c] = acc[c] * inv;
}

// qg_all[b][head][t][c] = mean over patches of q; layout [B][8][1024][32]
__global__ __launch_bounds__(256) void msa_qg_reduce_r6(
    const float* __restrict__ xq, float* __restrict__ qg_all, int head, int p)
{
  const int e = blockIdx.x * 256 + threadIdx.x;
  const int b = blockIdx.y;
  const int P2 = p * p;
  if (e >= P2 * 32) return;
  const int t = e >> 5, c = e & 31;
  const int nbp = 64 / p;
  const int hp = t / p, wp = t - (t / p) * p;
  float s = 0.f;
  for (int hb = 0; hb < nbp; ++hb)
    for (int wb = 0; wb < nbp; ++wb) {
      const int n = (hb * p + hp) * 64 + (wb * p + wp);
      s += xq[((size_t)b * 4096 + n) * 256 + head * 32 + c];
    }
  qg_all[((size_t)b * 8 + head) * 32768 + (size_t)t * 32 + c] = s / (float)(nbp * nbp);
}

// bilinear upsample (p x p -> 32 x 32), half-pixel centers + edge clamp
__global__ __launch_bounds__(256) void msa_qg_upsample_r6(
    const float* __restrict__ qg_all, float* __restrict__ Qg, int head, int p)
{
  const int e = blockIdx.x * 256 + threadIdx.x;  // 0..32767
  const int b = blockIdx.y;
  const int mlin = e >> 5, c = e & 31;
  const int mi = mlin >> 5, mj = mlin & 31;
  const float* src = qg_all + ((size_t)b * 8 + head) * 32768;
  float v;
  if (p == 32) {
    v = src[(size_t)mlin * 32 + c];
  } else {
    const float s = (float)p / 32.0f;
    const float xf = (mj + 0.5f) * s - 0.5f;
    const float yf = (mi + 0.5f) * s - 0.5f;
    const float xfl = floorf(xf), yfl = floorf(yf);
    const float fx = xf - xfl, fy = yf - yfl;
    const int x0 = (int)xfl, y0 = (int)yfl;
    const int x0c = max(0, min(p - 1, x0)), x1c = max(0, min(p - 1, x0 + 1));
    const int y0c = max(0, min(p - 1, y0)), y1c = max(0, min(p - 1, y0 + 1));
    const float v00 = src[(size_t)(y0c * p + x0c) * 32 + c];
    const float v01 = src[(size_t)(y0c * p + x1c) * 32 + c];
    const float v10 = src[(size_t)(y1c * p + x0c) * 32 + c];
    const float v11 = src[(size_t)(y1c * p + x1c) * 32 + c];
    v = (1.f - fy) * ((1.f - fx) * v00 + fx * v01)
      + fy * ((1.f - fx) * v10 + fx * v11);
  }
  Qg[((size_t)b * 1024 + mlin) * 256 + head * 32 + c] = v;
}

// 2x2 avg pool over the n'-grid (64x64, row-major) -> pooled [B,1024,256]
__global__ __launch_bounds__(256) void msa_pool_r6(
    const float* __restrict__ attn, float* __restrict__ pooled)
{
  const int c = threadIdx.x;
  const int mlin = blockIdx.x;
  const int b = blockIdx.y;
  const int mi = mlin >> 5, mj = mlin & 31;
  const size_t base = (size_t)b * 4096;
  const int r0 = mi * 2, q0 = mj * 2;
  float s = attn[(base + (r0 * 64 + q0)) * 256 + c]
          + attn[(base + (r0 * 64 + q0 + 1)) * 256 + c]
          + attn[(base + ((r0 + 1) * 64 + q0)) * 256 + c]
          + attn[(base + ((r0 + 1) * 64 + q0 + 1)) * 256 + c];
  pooled[((size_t)b * 1024 + mlin) * 256 + c] = s * 0.25f;
}

// attn[n] += bilinear_upsample(gl, 32->64)[n]
__global__ __launch_bounds__(256) void msa_blend_r6(
    const float* __restrict__ gl, float* __restrict__ attn)
{
  const int c = threadIdx.x;
  const int n = blockIdx.x;
  const int b = blockIdx.y;
  const int h = n >> 6, w = n & 63;
  const float xf = (w + 0.5f) * 0.5f - 0.5f;
  const float yf = (h + 0.5f) * 0.5f - 0.5f;
  const float xfl = floorf(xf), yfl = floorf(yf);
  const float fx = xf - xfl, fy = yf - yfl;
  const int x0 = (int)xfl, y0 = (int)yfl;
  const int x0c = max(0, min(31, x0)), x1c = max(0, min(31, x0 + 1));
  const int y0c = max(0, min(31, y0)), y1c = max(0, min(31, y0 + 1));
  const float* g = gl + (size_t)b * 1024 * 256;
  const float v00 = g[(size_t)(y0c * 32 + x0c) * 256 + c];
  const float v01 = g[(size_t)(y0c * 32 + x1c) * 256 + c];
  const float v10 = g[(size_t)(y1c * 32 + x0c) * 256 + c];
  const float v11 = g[(size_t)(y1c * 32 + x1c) * 256 + c];
  const float v = (1.f - fy) * ((1.f - fx) * v00 + fx * v01)
                + fy * ((1.f - fx) * v10 + fx * v11);
  attn[((size_t)b * 4096 + n) * 256 + c] += v;
}

extern "C" void kernel_launch(void* const* d_in, const int* in_sizes, int n_in,
                              void* d_out, int out_size, void* d_ws, size_t ws_size,
                              hipStream_t stream)
{
  const float* x     = (const float*)d_in[0];
  const float* Wq    = (const float*)d_in[1];
  const float* Wkv   = (const float*)d_in[2];
  const float* Wlkv  = (const float*)d_in[3];
  const float* Wproj = (const float*)d_in[4];
  const float* bproj = (const float*)d_in[5];

  char* ws = (char*)d_ws;
  // round-1 layout (proven to execute), all fp32, peak 151.0 MB:
  float* xq     = (float*)(ws + 0);             // [32768,256]
  float* xkv    = (float*)(ws + 33554432ull);   // [32768,512]
  float* attn   = (float*)(ws + 100663296ull);  // [32768,256]
  float* Qg     = (float*)(ws + 134217728ull);  // [8192,256]
  float* qg_all = (float*)(ws + 142606336ull);  // [8,8,1024,32]
  // overlays on regions dead after local attention:
  float* pooled = (float*)(ws + 0);             // over xq
  float* gl     = (float*)(ws + 8388608ull);    // over xq+8.4MB
  float* kv2    = (float*)(ws + 33554432ull);   // over xkv

  // 1) projections
  msa_gemm_r6<<<dim3(32768, 1), 256, 0, stream>>>(x, Wq, xq, 256, 256);
  msa_gemm_r6<<<dim3(32768, 2), 256, 0, stream>>>(x, Wkv, xkv, 256, 512);

  // 2) global-query means + bilinear upsample to Qg
  msa_qg_reduce_r6<<<dim3(2, 8),   256, 0, stream>>>(xq, qg_all, 0, 4);
  msa_qg_reduce_r6<<<dim3(2, 8),   256, 0, stream>>>(xq, qg_all, 1, 4);
  msa_qg_reduce_r6<<<dim3(8, 8),   256, 0, stream>>>(xq, qg_all, 2, 8);
  msa_qg_reduce_r6<<<dim3(8, 8),   256, 0, stream>>>(xq, qg_all, 3, 8);
  msa_qg_reduce_r6<<<dim3(32, 8),  256, 0, stream>>>(xq, qg_all, 4, 16);
  msa_qg_reduce_r6<<<dim3(32, 8),  256, 0, stream>>>(xq, qg_all, 5, 16);
  msa_qg_reduce_r6<<<dim3(128, 8), 256, 0, stream>>>(xq, qg_all, 6, 32);
  msa_qg_reduce_r6<<<dim3(128, 8), 256, 0, stream>>>(xq, qg_all, 7, 32);
  msa_qg_upsample_r6<<<dim3(128, 8), 256, 0, stream>>>(qg_all, Qg, 0, 4);
  msa_qg_upsample_r6<<<dim3(128, 8), 256, 0, stream>>>(qg_all, Qg, 1, 4);
  msa_qg_upsample_r6<<<dim3(128, 8), 256, 0, stream>>>(qg_all, Qg, 2, 8);
  msa_qg_upsample_r6<<<dim3(128, 8), 256, 0, stream>>>(qg_all, Qg, 3, 8);
  msa_qg_upsample_r6<<<dim3(128, 8), 256, 0, stream>>>(qg_all, Qg, 4, 16);
  msa_qg_upsample_r6<<<dim3(128, 8), 256, 0, stream>>>(qg_all, Qg, 5, 16);
  msa_qg_upsample_r6<<<dim3(128, 8), 256, 0, stream>>>(qg_all, Qg, 6, 32);
  msa_qg_upsample_r6<<<dim3(128, 8), 256, 0, stream>>>(qg_all, Qg, 7, 32);

  // 3) local windowed attention (patch-order rows)
  msa_attn_r6<<<dim3(64, 8), 64, 0, stream>>>(xq, xkv, attn, 0, 4, 0);
  msa_attn_r6<<<dim3(64, 8), 64, 0, stream>>>(xq, xkv, attn, 1, 4, 0);
  msa_attn_r6<<<dim3(64, 8), 64, 0, stream>>>(xq, xkv, attn, 2, 8, 0);
  msa_attn_r6<<<dim3(64, 8), 64, 0, stream>>>(xq, xkv, attn, 3, 8, 0);
  msa_attn_r6<<<dim3(64, 8), 64, 0, stream>>>(xq, xkv, attn, 4, 16, 0);
  msa_attn_r6<<<dim3(64, 8), 64, 0, stream>>>(xq, xkv, attn, 5, 16, 0);
  msa_attn_r6<<<dim3(64, 8), 64, 0, stream>>>(xq, xkv, attn, 6, 32, 0);
  msa_attn_r6<<<dim3(64, 8), 64, 0, stream>>>(xq, xkv, attn, 7, 32, 0);

  // 4) pool + kv2 projection (pooled/kv2 overlay xq/xkv after last use)
  msa_pool_r6<<<dim3(1024, 8), 256, 0, stream>>>(attn, pooled);
  msa_gemm_r6<<<dim3(8192, 2), 256, 0, stream>>>(pooled, Wlkv, kv2, 256, 512);

  // 5) global cross-attention -> gl
  msa_attn_r6<<<dim3(16, 8), 64, 0, stream>>>(Qg, kv2, gl, 0, 0, 1);
  msa_attn_r6<<<dim3(16, 8), 64, 0, stream>>>(Qg, kv2, gl, 1, 0, 1);
  msa_attn_r6<<<dim3(16, 8), 64, 0, stream>>>(Qg, kv2, gl, 2, 0, 1);
  msa_attn_r6<<<dim3(16, 8), 64, 0, stream>>>(Qg, kv2, gl, 3, 0, 1);
  msa_attn_r6<<<dim3(16, 8), 64, 0, stream>>>(Qg, kv2, gl, 4, 0, 1);
  msa_attn_r6<<<dim3(16, 8), 64, 0, stream>>>(Qg, kv2, gl, 5, 0, 1);
  msa_attn_r6<<<dim3(16, 8), 64, 0, stream>>>(Qg, kv2, gl, 6, 0, 1);
  msa_attn_r6<<<dim3(16, 8), 64, 0, stream>>>(Qg, kv2, gl, 7, 0, 1);

  // 6) blend + final projection (FP32 output)
  msa_blend_r6<<<dim3(4096, 8), 256, 0, stream>>>(gl, attn);
  msa_gemm_out_r6<<<dim3(32768, 1), 256, 0, stream>>>(
      attn, Wproj, bproj, (float*)d_out, 256, 256);

  (void)in_sizes; (void)n_in; (void)out_size; (void)ws_size;
}

// Round 7
// 1949.812 us; speedup vs baseline: 6.1530x; 6.1530x over previous
//
#include <hip/hip_runtime.h>
#include <hip/hip_bf16.h>
#include <math.h>

// ---------------------------------------------------------------------------
// ROUND 7: fp32 pipeline, optimized.
//  - 64x64 LDS-tiled fp32 GEMM (4x4 acc/thread, 256 threads)
//  - attention: heads fused via blockIdx.z, float4 loads, 4-way dot chains
//  - 10 launches total (was 51)
// Output fp32. Workspace layout = round 6 (proven). Fresh _r7 names.
// ---------------------------------------------------------------------------

// C[M,N] = A[M,K] @ W[K,N] (+bias if non-null), fp32. grid=(N/64, M/64)
__global__ __launch_bounds__(256) void msa_gemm_t_r7(
    const float* __restrict__ A, const float* __restrict__ W,
    const float* __restrict__ bias, float* __restrict__ C, int K, int N)
{
  __shared__ __align__(16) float As[16][64];   // [k][m]
  __shared__ __align__(16) float Ws[16][64];   // [k][n]
  const int tid = threadIdx.x;
  const int tx = tid & 15, ty = tid >> 4;
  const int bm = blockIdx.y * 64;
  const int bn = blockIdx.x * 64;
  const int arow = tid >> 2;          // 0..63
  const int acol = (tid & 3) << 2;    // 0,4,8,12
  const int wrow = tid >> 4;          // 0..15
  const int wcol = (tid & 15) << 2;   // 0..60
  float acc[4][4] = {};
  for (int k0 = 0; k0 < K; k0 += 16) {
    const float4 av = *reinterpret_cast<const float4*>(&A[(size_t)(bm + arow) * K + k0 + acol]);
    const float4 wv = *reinterpret_cast<const float4*>(&W[(size_t)(k0 + wrow) * N + bn + wcol]);
    __syncthreads();
    As[acol + 0][arow] = av.x;
    As[acol + 1][arow] = av.y;
    As[acol + 2][arow] = av.z;
    As[acol + 3][arow] = av.w;
    *reinterpret_cast<float4*>(&Ws[wrow][wcol]) = wv;
    __syncthreads();
#pragma unroll
    for (int kk = 0; kk < 16; ++kk) {
      const float4 a4 = *reinterpret_cast<const float4*>(&As[kk][ty * 4]);
      const float4 w4 = *reinterpret_cast<const float4*>(&Ws[kk][tx * 4]);
      const float a[4] = {a4.x, a4.y, a4.z, a4.w};
      const float w[4] = {w4.x, w4.y, w4.z, w4.w};
#pragma unroll
      for (int i = 0; i < 4; ++i)
#pragma unroll
        for (int j = 0; j < 4; ++j)
          acc[i][j] = fmaf(a[i], w[j], acc[i][j]);
    }
  }
#pragma unroll
  for (int i = 0; i < 4; ++i) {
    const int row = bm + ty * 4 + i;
#pragma unroll
    for (int j = 0; j < 4; ++j) {
      const int col = bn + tx * 4 + j;
      float v = acc[i][j];
      if (bias) v += bias[col];
      C[(size_t)row * N + col] = v;
    }
  }
}

// attention, one thread per query row, head = blockIdx.z.
// mode 0: local windowed (PATCH-order rows), NTOK=4096.
// mode 1: global, NTOK=1024, P2=1024.
__global__ __launch_bounds__(64) void msa_attn_r7(
    const float* __restrict__ qsrc, const float* __restrict__ kvsrc,
    float* __restrict__ out, int mode)
{
  const int head = blockIdx.z;
  const int p = (head < 2) ? 4 : (head < 4) ? 8 : (head < 6) ? 16 : 32;
  const int b = blockIdx.y;
  const int nq = blockIdx.x * 64 + threadIdx.x;
  const int NTOK = mode ? 1024 : 4096;
  const int P2 = mode ? 1024 : p * p;

  int n, hb = 0, wb = 0;
  if (mode) {
    n = nq;
  } else {
    const int patch = nq / P2;
    const int t = nq - patch * P2;
    const int nbp = 64 / p;
    hb = patch / nbp;
    wb = patch - hb * nbp;
    const int hp = t / p;
    const int wp = t - hp * p;
    n = (hb * p + hp) * 64 + (wb * p + wp);
  }

  const float4* q4 = reinterpret_cast<const float4*>(
      qsrc + ((size_t)b * NTOK + n) * 256 + head * 32);
  float4 qv[8];
#pragma unroll
  for (int i = 0; i < 8; ++i) qv[i] = q4[i];

  const float scale = 0.17677669529663687f;  // 32^-0.5
  float m = -3.0e38f, l = 0.f;
  float4 acc4[8];
#pragma unroll
  for (int i = 0; i < 8; ++i) acc4[i] = make_float4(0.f, 0.f, 0.f, 0.f);

  for (int kk = 0; kk < P2; ++kk) {
    int nk;
    if (mode) {
      nk = kk;
    } else {
      const int khp = kk / p;
      const int kwp = kk - khp * p;
      nk = (hb * p + khp) * 64 + (wb * p + kwp);
    }
    const float4* kv4 = reinterpret_cast<const float4*>(
        kvsrc + ((size_t)b * NTOK + nk) * 512 + head * 32);
    float s0 = 0.f, s1 = 0.f, s2 = 0.f, s3 = 0.f;
#pragma unroll
    for (int i = 0; i < 8; ++i) {
      const float4 k4 = kv4[i];
      s0 = fmaf(qv[i].x, k4.x, s0);
      s1 = fmaf(qv[i].y, k4.y, s1);
      s2 = fmaf(qv[i].z, k4.z, s2);
      s3 = fmaf(qv[i].w, k4.w, s3);
    }
    const float s = ((s0 + s1) + (s2 + s3)) * scale;
    const float mnew = fmaxf(m, s);
    const float f  = __expf(m - mnew);
    const float pe = __expf(s - mnew);
    l = l * f + pe;
#pragma unroll
    for (int i = 0; i < 8; ++i) {
      const float4 v4 = kv4[64 + i];   // +256 floats
      acc4[i].x = fmaf(acc4[i].x, f, pe * v4.x);
      acc4[i].y = fmaf(acc4[i].y, f, pe * v4.y);
      acc4[i].z = fmaf(acc4[i].z, f, pe * v4.z);
      acc4[i].w = fmaf(acc4[i].w, f, pe * v4.w);
    }
    m = mnew;
  }

  const float inv = 1.f / l;
  float4* dst = reinterpret_cast<float4*>(
      out + ((size_t)b * NTOK + nq) * 256 + head * 32);
#pragma unroll
  for (int i = 0; i < 8; ++i) {
    float4 o = acc4[i];
    o.x *= inv; o.y *= inv; o.z *= inv; o.w *= inv;
    dst[i] = o;
  }
}

// qg_all[b][head][t][c] = mean over patches of q; layout [B][8][1024][32]
__global__ __launch_bounds__(256) void msa_qg_reduce_r7(
    const float* __restrict__ xq, float* __restrict__ qg_all)
{
  const int head = blockIdx.z;
  const int p = (head < 2) ? 4 : (head < 4) ? 8 : (head < 6) ? 16 : 32;
  const int e = blockIdx.x * 256 + threadIdx.x;
  const int b = blockIdx.y;
  const int P2 = p * p;
  if (e >= P2 * 32) return;
  const int t = e >> 5, c = e & 31;
  const int nbp = 64 / p;
  const int hp = t / p, wp = t - (t / p) * p;
  float s = 0.f;
  for (int hb = 0; hb < nbp; ++hb)
    for (int wb = 0; wb < nbp; ++wb) {
      const int n = (hb * p + hp) * 64 + (wb * p + wp);
      s += xq[((size_t)b * 4096 + n) * 256 + head * 32 + c];
    }
  qg_all[((size_t)b * 8 + head) * 32768 + (size_t)t * 32 + c] = s / (float)(nbp * nbp);
}

// bilinear upsample (p x p -> 32 x 32), half-pixel centers + edge clamp
__global__ __launch_bounds__(256) void msa_qg_upsample_r7(
    const float* __restrict__ qg_all, float* __restrict__ Qg)
{
  const int head = blockIdx.z;
  const int p = (head < 2) ? 4 : (head < 4) ? 8 : (head < 6) ? 16 : 32;
  const int e = blockIdx.x * 256 + threadIdx.x;  // 0..32767
  const int b = blockIdx.y;
  const int mlin = e >> 5, c = e & 31;
  const int mi = mlin >> 5, mj = mlin & 31;
  const float* src = qg_all + ((size_t)b * 8 + head) * 32768;
  float v;
  if (p == 32) {
    v = src[(size_t)mlin * 32 + c];
  } else {
    const float s = (float)p / 32.0f;
    const float xf = (mj + 0.5f) * s - 0.5f;
    const float yf = (mi + 0.5f) * s - 0.5f;
    const float xfl = floorf(xf), yfl = floorf(yf);
    const float fx = xf - xfl, fy = yf - yfl;
    const int x0 = (int)xfl, y0 = (int)yfl;
    const int x0c = max(0, min(p - 1, x0)), x1c = max(0, min(p - 1, x0 + 1));
    const int y0c = max(0, min(p - 1, y0)), y1c = max(0, min(p - 1, y0 + 1));
    const float v00 = src[(size_t)(y0c * p + x0c) * 32 + c];
    const float v01 = src[(size_t)(y0c * p + x1c) * 32 + c];
    const float v10 = src[(size_t)(y1c * p + x0c) * 32 + c];
    const float v11 = src[(size_t)(y1c * p + x1c) * 32 + c];
    v = (1.f - fy) * ((1.f - fx) * v00 + fx * v01)
      + fy * ((1.f - fx) * v10 + fx * v11);
  }
  Qg[((size_t)b * 1024 + mlin) * 256 + head * 32 + c] = v;
}

// 2x2 avg pool over the n'-grid (64x64, row-major) -> pooled [B,1024,256]
__global__ __launch_bounds__(256) void msa_pool_r7(
    const float* __restrict__ attn, float* __restrict__ pooled)
{
  const int c = threadIdx.x;
  const int mlin = blockIdx.x;
  const int b = blockIdx.y;
  const int mi = mlin >> 5, mj = mlin & 31;
  const size_t base = (size_t)b * 4096;
  const int r0 = mi * 2, q0 = mj * 2;
  float s = attn[(base + (r0 * 64 + q0)) * 256 + c]
          + attn[(base + (r0 * 64 + q0 + 1)) * 256 + c]
          + attn[(base + ((r0 + 1) * 64 + q0)) * 256 + c]
          + attn[(base + ((r0 + 1) * 64 + q0 + 1)) * 256 + c];
  pooled[((size_t)b * 1024 + mlin) * 256 + c] = s * 0.25f;
}

// attn[n] += bilinear_upsample(gl, 32->64)[n]
__global__ __launch_bounds__(256) void msa_blend_r7(
    const float* __restrict__ gl, float* __restrict__ attn)
{
  const int c = threadIdx.x;
  const int n = blockIdx.x;
  const int b = blockIdx.y;
  const int h = n >> 6, w = n & 63;
  const float xf = (w + 0.5f) * 0.5f - 0.5f;
  const float yf = (h + 0.5f) * 0.5f - 0.5f;
  const float xfl = floorf(xf), yfl = floorf(yf);
  const float fx = xf - xfl, fy = yf - yfl;
  const int x0 = (int)xfl, y0 = (int)yfl;
  const int x0c = max(0, min(31, x0)), x1c = max(0, min(31, x0 + 1));
  const int y0c = max(0, min(31, y0)), y1c = max(0, min(31, y0 + 1));
  const float* g = gl + (size_t)b * 1024 * 256;
  const float v00 = g[(size_t)(y0c * 32 + x0c) * 256 + c];
  const float v01 = g[(size_t)(y0c * 32 + x1c) * 256 + c];
  const float v10 = g[(size_t)(y1c * 32 + x0c) * 256 + c];
  const float v11 = g[(size_t)(y1c * 32 + x1c) * 256 + c];
  const float v = (1.f - fy) * ((1.f - fx) * v00 + fx * v01)
                + fy * ((1.f - fx) * v10 + fx * v11);
  attn[((size_t)b * 4096 + n) * 256 + c] += v;
}

extern "C" void kernel_launch(void* const* d_in, const int* in_sizes, int n_in,
                              void* d_out, int out_size, void* d_ws, size_t ws_size,
                              hipStream_t stream)
{
  const float* x     = (const float*)d_in[0];
  const float* Wq    = (const float*)d_in[1];
  const float* Wkv   = (const float*)d_in[2];
  const float* Wlkv  = (const float*)d_in[3];
  const float* Wproj = (const float*)d_in[4];
  const float* bproj = (const float*)d_in[5];

  char* ws = (char*)d_ws;
  // all fp32, peak 151.0 MB (proven to fit):
  float* xq     = (float*)(ws + 0);             // [32768,256]
  float* xkv    = (float*)(ws + 33554432ull);   // [32768,512]
  float* attn   = (float*)(ws + 100663296ull);  // [32768,256]
  float* Qg     = (float*)(ws + 134217728ull);  // [8192,256]
  float* qg_all = (float*)(ws + 142606336ull);  // [8,8,1024,32]
  // overlays on regions dead after local attention:
  float* pooled = (float*)(ws + 0);             // over xq
  float* gl     = (float*)(ws + 8388608ull);    // over xq+8.4MB
  float* kv2    = (float*)(ws + 33554432ull);   // over xkv

  // 1) projections (tiled)
  msa_gemm_t_r7<<<dim3(4, 512), 256, 0, stream>>>(x, Wq, nullptr, xq, 256, 256);
  msa_gemm_t_r7<<<dim3(8, 512), 256, 0, stream>>>(x, Wkv, nullptr, xkv, 256, 512);

  // 2) global-query means + bilinear upsample (heads fused via grid.z)
  msa_qg_reduce_r7<<<dim3(128, 8, 8), 256, 0, stream>>>(xq, qg_all);
  msa_qg_upsample_r7<<<dim3(128, 8, 8), 256, 0, stream>>>(qg_all, Qg);

  // 3) local windowed attention (one launch, all heads)
  msa_attn_r7<<<dim3(64, 8, 8), 64, 0, stream>>>(xq, xkv, attn, 0);

  // 4) pool + kv2 projection
  msa_pool_r7<<<dim3(1024, 8), 256, 0, stream>>>(attn, pooled);
  msa_gemm_t_r7<<<dim3(8, 128), 256, 0, stream>>>(pooled, Wlkv, nullptr, kv2, 256, 512);

  // 5) global cross-attention (one launch, all heads)
  msa_attn_r7<<<dim3(16, 8, 8), 64, 0, stream>>>(Qg, kv2, gl, 1);

  // 6) blend + final projection (fp32 out, bias)
  msa_blend_r7<<<dim3(4096, 8), 256, 0, stream>>>(gl, attn);
  msa_gemm_t_r7<<<dim3(4, 512), 256, 0, stream>>>(
      attn, Wproj, bproj, (float*)d_out, 256, 256);

  (void)in_sizes; (void)n_in; (void)out_size; (void)ws_size;
}

// Round 8
// 1224.061 us; speedup vs baseline: 9.8012x; 1.5929x over previous
//
#include <hip/hip_runtime.h>
#include <hip/hip_bf16.h>
#include <math.h>

// ---------------------------------------------------------------------------
// ROUND 8: fp32 pipeline; attention rewritten.
//  - big heads (p=16,32) + global attn: 256-thr blocks, 128-key LDS chunks,
//    branch-skip online softmax (rescale only on new max)
//  - small heads (p=4,8): register-direct + branch-skip
//  - GEMMs/pool/blend/qg unchanged from r7 (renamed _r8 to force rebuild)
// ---------------------------------------------------------------------------

// C[M,N] = A[M,K] @ W[K,N] (+bias if non-null), fp32. grid=(N/64, M/64)
__global__ __launch_bounds__(256) void msa_gemm_t_r8(
    const float* __restrict__ A, const float* __restrict__ W,
    const float* __restrict__ bias, float* __restrict__ C, int K, int N)
{
  __shared__ __align__(16) float As[16][64];   // [k][m]
  __shared__ __align__(16) float Ws[16][64];   // [k][n]
  const int tid = threadIdx.x;
  const int tx = tid & 15, ty = tid >> 4;
  const int bm = blockIdx.y * 64;
  const int bn = blockIdx.x * 64;
  const int arow = tid >> 2;
  const int acol = (tid & 3) << 2;
  const int wrow = tid >> 4;
  const int wcol = (tid & 15) << 2;
  float acc[4][4] = {};
  for (int k0 = 0; k0 < K; k0 += 16) {
    const float4 av = *reinterpret_cast<const float4*>(&A[(size_t)(bm + arow) * K + k0 + acol]);
    const float4 wv = *reinterpret_cast<const float4*>(&W[(size_t)(k0 + wrow) * N + bn + wcol]);
    __syncthreads();
    As[acol + 0][arow] = av.x;
    As[acol + 1][arow] = av.y;
    As[acol + 2][arow] = av.z;
    As[acol + 3][arow] = av.w;
    *reinterpret_cast<float4*>(&Ws[wrow][wcol]) = wv;
    __syncthreads();
#pragma unroll
    for (int kk = 0; kk < 16; ++kk) {
      const float4 a4 = *reinterpret_cast<const float4*>(&As[kk][ty * 4]);
      const float4 w4 = *reinterpret_cast<const float4*>(&Ws[kk][tx * 4]);
      const float a[4] = {a4.x, a4.y, a4.z, a4.w};
      const float w[4] = {w4.x, w4.y, w4.z, w4.w};
#pragma unroll
      for (int i = 0; i < 4; ++i)
#pragma unroll
        for (int j = 0; j < 4; ++j)
          acc[i][j] = fmaf(a[i], w[j], acc[i][j]);
    }
  }
#pragma unroll
  for (int i = 0; i < 4; ++i) {
    const int row = bm + ty * 4 + i;
#pragma unroll
    for (int j = 0; j < 4; ++j) {
      const int col = bn + tx * 4 + j;
      float v = acc[i][j];
      if (bias) v += bias[col];
      C[(size_t)row * N + col] = v;
    }
  }
}

// ---- small heads (p=4 or 8), register-direct, one thread per query --------
__global__ __launch_bounds__(64) void msa_attn_small_r8(
    const float* __restrict__ xq, const float* __restrict__ xkv,
    float* __restrict__ out)
{
  const int head = blockIdx.z;               // 0..3
  const int p = (head < 2) ? 4 : 8;
  const int b = blockIdx.y;
  const int nq = blockIdx.x * 64 + threadIdx.x;
  const int P2 = p * p;

  const int patch = nq / P2;
  const int t = nq - patch * P2;
  const int nbp = 64 / p;
  const int hb = patch / nbp;
  const int wb = patch - hb * nbp;
  const int n = (hb * p + t / p) * 64 + (wb * p + t - (t / p) * p);

  const float4* q4 = reinterpret_cast<const float4*>(
      xq + ((size_t)b * 4096 + n) * 256 + head * 32);
  float4 qv[8];
#pragma unroll
  for (int i = 0; i < 8; ++i) qv[i] = q4[i];

  const float scale = 0.17677669529663687f;
  float m = -3.0e38f, l = 0.f;
  float4 acc4[8];
#pragma unroll
  for (int i = 0; i < 8; ++i) acc4[i] = make_float4(0.f, 0.f, 0.f, 0.f);

  const int kbase = (hb * p) * 64 + wb * p;
  for (int kk = 0; kk < P2; ++kk) {
    const int nk = kbase + (kk / p) * 64 + (kk - (kk / p) * p);
    const float4* kv4 = reinterpret_cast<const float4*>(
        xkv + ((size_t)b * 4096 + nk) * 512 + head * 32);
    float s0 = 0.f, s1 = 0.f, s2 = 0.f, s3 = 0.f;
#pragma unroll
    for (int i = 0; i < 8; ++i) {
      const float4 k4 = kv4[i];
      s0 = fmaf(qv[i].x, k4.x, s0);
      s1 = fmaf(qv[i].y, k4.y, s1);
      s2 = fmaf(qv[i].z, k4.z, s2);
      s3 = fmaf(qv[i].w, k4.w, s3);
    }
    const float s = ((s0 + s1) + (s2 + s3)) * scale;
    if (s <= m) {
      const float pe = __expf(s - m);
      l += pe;
#pragma unroll
      for (int i = 0; i < 8; ++i) {
        const float4 v4 = kv4[64 + i];
        acc4[i].x = fmaf(pe, v4.x, acc4[i].x);
        acc4[i].y = fmaf(pe, v4.y, acc4[i].y);
        acc4[i].z = fmaf(pe, v4.z, acc4[i].z);
        acc4[i].w = fmaf(pe, v4.w, acc4[i].w);
      }
    } else {
      const float f = __expf(m - s);
      l = fmaf(l, f, 1.f);
#pragma unroll
      for (int i = 0; i < 8; ++i) {
        const float4 v4 = kv4[64 + i];
        acc4[i].x = fmaf(acc4[i].x, f, v4.x);
        acc4[i].y = fmaf(acc4[i].y, f, v4.y);
        acc4[i].z = fmaf(acc4[i].z, f, v4.z);
        acc4[i].w = fmaf(acc4[i].w, f, v4.w);
      }
      m = s;
    }
  }

  const float inv = 1.f / l;
  float4* dst = reinterpret_cast<float4*>(
      out + ((size_t)b * 4096 + nq) * 256 + head * 32);
#pragma unroll
  for (int i = 0; i < 8; ++i) {
    float4 o = acc4[i];
    o.x *= inv; o.y *= inv; o.z *= inv; o.w *= inv;
    dst[i] = o;
  }
}

// ---- big heads (p=16,32) and global attention: LDS 128-key chunks ---------
// mode 0: heads 4..7 (p=16,16,32,32), qsrc=xq, kvsrc=xkv, NTOK=4096
// mode 1: heads 0..7 global, qsrc=Qg, kvsrc=kv2, NTOK=1024, P2=1024
__global__ __launch_bounds__(256) void msa_attn_big_r8(
    const float* __restrict__ qsrc, const float* __restrict__ kvsrc,
    float* __restrict__ out, int mode)
{
  __shared__ __align__(16) float kv[128 * 64];   // [key][0..31]=k, [32..63]=v
  const int tid = threadIdx.x;
  const int b = blockIdx.y;

  int head, NTOK, P2, lp, pm1, n, base;
  const int nq = blockIdx.x * 256 + tid;
  if (mode) {
    head = blockIdx.z;
    NTOK = 1024; P2 = 1024; lp = 0; pm1 = 0; base = 0;
    n = nq;
  } else {
    head = 4 + blockIdx.z;
    lp = (head < 6) ? 4 : 5;           // p = 16 or 32
    const int p = 1 << lp;
    pm1 = p - 1;
    NTOK = 4096; P2 = p * p;
    const int patch = nq >> (2 * lp);
    const int t = nq & (P2 - 1);
    const int nbp = 64 >> lp;
    const int hb = patch / nbp, wb = patch - (patch / nbp) * nbp;
    base = (hb * p) * 64 + wb * p;
    n = base + (t >> lp) * 64 + (t & pm1);
  }

  const float4* q4 = reinterpret_cast<const float4*>(
      qsrc + ((size_t)b * NTOK + n) * 256 + head * 32);
  float4 qv[8];
#pragma unroll
  for (int i = 0; i < 8; ++i) qv[i] = q4[i];

  const float scale = 0.17677669529663687f;
  float m = -3.0e38f, l = 0.f;
  float4 acc4[8];
#pragma unroll
  for (int i = 0; i < 8; ++i) acc4[i] = make_float4(0.f, 0.f, 0.f, 0.f);

  for (int kc = 0; kc < P2; kc += 128) {
    __syncthreads();
    // stage 128 keys (k+v): 8192 floats, 8 float4 per thread, coalesced
#pragma unroll
    for (int i = 0; i < 8; ++i) {
      const int slot = tid + i * 256;     // 0..2047
      const int key = slot >> 4;          // 0..127
      const int part = slot & 15;         // 0..15 (0-7: k, 8-15: v)
      const int kk = kc + key;
      const int nk = mode ? kk : base + (kk >> lp) * 64 + (kk & pm1);
      const float* src = kvsrc + ((size_t)b * NTOK + nk) * 512 + head * 32
                       + (part < 8 ? part * 4 : 256 + (part - 8) * 4);
      reinterpret_cast<float4*>(kv)[slot] = *reinterpret_cast<const float4*>(src);
    }
    __syncthreads();
    for (int key = 0; key < 128; ++key) {
      const float4* kk4 = reinterpret_cast<const float4*>(kv + key * 64);
      float s0 = 0.f, s1 = 0.f, s2 = 0.f, s3 = 0.f;
#pragma unroll
      for (int i = 0; i < 8; ++i) {
        const float4 k4 = kk4[i];
        s0 = fmaf(qv[i].x, k4.x, s0);
        s1 = fmaf(qv[i].y, k4.y, s1);
        s2 = fmaf(qv[i].z, k4.z, s2);
        s3 = fmaf(qv[i].w, k4.w, s3);
      }
      const float s = ((s0 + s1) + (s2 + s3)) * scale;
      if (s <= m) {
        const float pe = __expf(s - m);
        l += pe;
#pragma unroll
        for (int i = 0; i < 8; ++i) {
          const float4 v4 = kk4[8 + i];
          acc4[i].x = fmaf(pe, v4.x, acc4[i].x);
          acc4[i].y = fmaf(pe, v4.y, acc4[i].y);
          acc4[i].z = fmaf(pe, v4.z, acc4[i].z);
          acc4[i].w = fmaf(pe, v4.w, acc4[i].w);
        }
      } else {
        const float f = __expf(m - s);
        l = fmaf(l, f, 1.f);
#pragma unroll
        for (int i = 0; i < 8; ++i) {
          const float4 v4 = kk4[8 + i];
          acc4[i].x = fmaf(acc4[i].x, f, v4.x);
          acc4[i].y = fmaf(acc4[i].y, f, v4.y);
          acc4[i].z = fmaf(acc4[i].z, f, v4.z);
          acc4[i].w = fmaf(acc4[i].w, f, v4.w);
        }
        m = s;
      }
    }
  }

  const float inv = 1.f / l;
  float4* dst = reinterpret_cast<float4*>(
      out + ((size_t)b * NTOK + nq) * 256 + head * 32);
#pragma unroll
  for (int i = 0; i < 8; ++i) {
    float4 o = acc4[i];
    o.x *= inv; o.y *= inv; o.z *= inv; o.w *= inv;
    dst[i] = o;
  }
}

// qg_all[b][head][t][c] = mean over patches of q; layout [B][8][1024][32]
__global__ __launch_bounds__(256) void msa_qg_reduce_r8(
    const float* __restrict__ xq, float* __restrict__ qg_all)
{
  const int head = blockIdx.z;
  const int p = (head < 2) ? 4 : (head < 4) ? 8 : (head < 6) ? 16 : 32;
  const int e = blockIdx.x * 256 + threadIdx.x;
  const int b = blockIdx.y;
  const int P2 = p * p;
  if (e >= P2 * 32) return;
  const int t = e >> 5, c = e & 31;
  const int nbp = 64 / p;
  const int hp = t / p, wp = t - (t / p) * p;
  float s = 0.f;
  for (int hb = 0; hb < nbp; ++hb)
    for (int wb = 0; wb < nbp; ++wb) {
      const int n = (hb * p + hp) * 64 + (wb * p + wp);
      s += xq[((size_t)b * 4096 + n) * 256 + head * 32 + c];
    }
  qg_all[((size_t)b * 8 + head) * 32768 + (size_t)t * 32 + c] = s / (float)(nbp * nbp);
}

// bilinear upsample (p x p -> 32 x 32), half-pixel centers + edge clamp
__global__ __launch_bounds__(256) void msa_qg_upsample_r8(
    const float* __restrict__ qg_all, float* __restrict__ Qg)
{
  const int head = blockIdx.z;
  const int p = (head < 2) ? 4 : (head < 4) ? 8 : (head < 6) ? 16 : 32;
  const int e = blockIdx.x * 256 + threadIdx.x;
  const int b = blockIdx.y;
  const int mlin = e >> 5, c = e & 31;
  const int mi = mlin >> 5, mj = mlin & 31;
  const float* src = qg_all + ((size_t)b * 8 + head) * 32768;
  float v;
  if (p == 32) {
    v = src[(size_t)mlin * 32 + c];
  } else {
    const float s = (float)p / 32.0f;
    const float xf = (mj + 0.5f) * s - 0.5f;
    const float yf = (mi + 0.5f) * s - 0.5f;
    const float xfl = floorf(xf), yfl = floorf(yf);
    const float fx = xf - xfl, fy = yf - yfl;
    const int x0 = (int)xfl, y0 = (int)yfl;
    const int x0c = max(0, min(p - 1, x0)), x1c = max(0, min(p - 1, x0 + 1));
    const int y0c = max(0, min(p - 1, y0)), y1c = max(0, min(p - 1, y0 + 1));
    const float v00 = src[(size_t)(y0c * p + x0c) * 32 + c];
    const float v01 = src[(size_t)(y0c * p + x1c) * 32 + c];
    const float v10 = src[(size_t)(y1c * p + x0c) * 32 + c];
    const float v11 = src[(size_t)(y1c * p + x1c) * 32 + c];
    v = (1.f - fy) * ((1.f - fx) * v00 + fx * v01)
      + fy * ((1.f - fx) * v10 + fx * v11);
  }
  Qg[((size_t)b * 1024 + mlin) * 256 + head * 32 + c] = v;
}

// 2x2 avg pool over the n'-grid (64x64, row-major) -> pooled [B,1024,256]
__global__ __launch_bounds__(256) void msa_pool_r8(
    const float* __restrict__ attn, float* __restrict__ pooled)
{
  const int c = threadIdx.x;
  const int mlin = blockIdx.x;
  const int b = blockIdx.y;
  const int mi = mlin >> 5, mj = mlin & 31;
  const size_t base = (size_t)b * 4096;
  const int r0 = mi * 2, q0 = mj * 2;
  float s = attn[(base + (r0 * 64 + q0)) * 256 + c]
          + attn[(base + (r0 * 64 + q0 + 1)) * 256 + c]
          + attn[(base + ((r0 + 1) * 64 + q0)) * 256 + c]
          + attn[(base + ((r0 + 1) * 64 + q0 + 1)) * 256 + c];
  pooled[((size_t)b * 1024 + mlin) * 256 + c] = s * 0.25f;
}

// attn[n] += bilinear_upsample(gl, 32->64)[n]
__global__ __launch_bounds__(256) void msa_blend_r8(
    const float* __restrict__ gl, float* __restrict__ attn)
{
  const int c = threadIdx.x;
  const int n = blockIdx.x;
  const int b = blockIdx.y;
  const int h = n >> 6, w = n & 63;
  const float xf = (w + 0.5f) * 0.5f - 0.5f;
  const float yf = (h + 0.5f) * 0.5f - 0.5f;
  const float xfl = floorf(xf), yfl = floorf(yf);
  const float fx = xf - xfl, fy = yf - yfl;
  const int x0 = (int)xfl, y0 = (int)yfl;
  const int x0c = max(0, min(31, x0)), x1c = max(0, min(31, x0 + 1));
  const int y0c = max(0, min(31, y0)), y1c = max(0, min(31, y0 + 1));
  const float* g = gl + (size_t)b * 1024 * 256;
  const float v00 = g[(size_t)(y0c * 32 + x0c) * 256 + c];
  const float v01 = g[(size_t)(y0c * 32 + x1c) * 256 + c];
  const float v10 = g[(size_t)(y1c * 32 + x0c) * 256 + c];
  const float v11 = g[(size_t)(y1c * 32 + x1c) * 256 + c];
  const float v = (1.f - fy) * ((1.f - fx) * v00 + fx * v01)
                + fy * ((1.f - fx) * v10 + fx * v11);
  attn[((size_t)b * 4096 + n) * 256 + c] += v;
}

extern "C" void kernel_launch(void* const* d_in, const int* in_sizes, int n_in,
                              void* d_out, int out_size, void* d_ws, size_t ws_size,
                              hipStream_t stream)
{
  const float* x     = (const float*)d_in[0];
  const float* Wq    = (const float*)d_in[1];
  const float* Wkv   = (const float*)d_in[2];
  const float* Wlkv  = (const float*)d_in[3];
  const float* Wproj = (const float*)d_in[4];
  const float* bproj = (const float*)d_in[5];

  char* ws = (char*)d_ws;
  float* xq     = (float*)(ws + 0);             // [32768,256]
  float* xkv    = (float*)(ws + 33554432ull);   // [32768,512]
  float* attn   = (float*)(ws + 100663296ull);  // [32768,256]
  float* Qg     = (float*)(ws + 134217728ull);  // [8192,256]
  float* qg_all = (float*)(ws + 142606336ull);  // [8,8,1024,32]
  float* pooled = (float*)(ws + 0);             // over xq (dead)
  float* gl     = (float*)(ws + 8388608ull);    // over xq+8.4MB
  float* kv2    = (float*)(ws + 33554432ull);   // over xkv (dead)

  // 1) projections (tiled)
  msa_gemm_t_r8<<<dim3(4, 512), 256, 0, stream>>>(x, Wq, nullptr, xq, 256, 256);
  msa_gemm_t_r8<<<dim3(8, 512), 256, 0, stream>>>(x, Wkv, nullptr, xkv, 256, 512);

  // 2) global-query means + bilinear upsample
  msa_qg_reduce_r8<<<dim3(128, 8, 8), 256, 0, stream>>>(xq, qg_all);
  msa_qg_upsample_r8<<<dim3(128, 8, 8), 256, 0, stream>>>(qg_all, Qg);

  // 3) local windowed attention
  msa_attn_small_r8<<<dim3(64, 8, 4), 64, 0, stream>>>(xq, xkv, attn);
  msa_attn_big_r8<<<dim3(16, 8, 4), 256, 0, stream>>>(xq, xkv, attn, 0);

  // 4) pool + kv2 projection
  msa_pool_r8<<<dim3(1024, 8), 256, 0, stream>>>(attn, pooled);
  msa_gemm_t_r8<<<dim3(8, 128), 256, 0, stream>>>(pooled, Wlkv, nullptr, kv2, 256, 512);

  // 5) global cross-attention
  msa_attn_big_r8<<<dim3(4, 8, 8), 256, 0, stream>>>(Qg, kv2, gl, 1);

  // 6) blend + final projection (fp32 out)
  msa_blend_r8<<<dim3(4096, 8), 256, 0, stream>>>(gl, attn);
  msa_gemm_t_r8<<<dim3(4, 512), 256, 0, stream>>>(
      attn, Wproj, bproj, (float*)d_out, 256, 256);

  (void)in_sizes; (void)n_in; (void)out_size; (void)ws_size;
}

// Round 9
// 561.477 us; speedup vs baseline: 21.3672x; 2.1801x over previous
//
#include <hip/hip_runtime.h>
#include <math.h>

// ---------------------------------------------------------------------------
// ROUND 9: attention on MFMA (bf16), fp32 online softmax.
//  - xq/xkv/Qg/kv2 stored bf16 (fp32 GEMM compute, bf16 store)
//  - big heads (p=16,32) + global attn: 4-wave blocks, 16q x 32k MFMA chunks,
//    swapped QK^T (S^T) so softmax is lane-local; PV via per-wave P_lds tile.
//    Layout-permutation-invariant operand packing (A/B share k-slot maps).
//  - small heads (p=4,8): register fp32 path, bf16 loads
// ---------------------------------------------------------------------------

typedef __attribute__((ext_vector_type(8))) short bf16x8;
typedef __attribute__((ext_vector_type(4))) float f32x4;

__device__ inline float bf2f(unsigned short u) {
  union { unsigned int i; float f; } v; v.i = ((unsigned int)u) << 16; return v.f;
}
__device__ inline unsigned short f2bf(float x) {
  union { float f; unsigned int i; } v; v.f = x;
  return (unsigned short)((v.i + 0x7FFFu + ((v.i >> 16) & 1u)) >> 16);
}

// C[M,N] = A[M,K] @ W[K,N] (+bias); store fp32 (Cf) or bf16 (Cb).
__global__ __launch_bounds__(256) void msa_gemm_r9(
    const float* __restrict__ A, const float* __restrict__ W,
    const float* __restrict__ bias, float* __restrict__ Cf,
    unsigned short* __restrict__ Cb, int K, int N)
{
  __shared__ __align__(16) float As[16][64];
  __shared__ __align__(16) float Ws[16][64];
  const int tid = threadIdx.x;
  const int tx = tid & 15, ty = tid >> 4;
  const int bm = blockIdx.y * 64, bn = blockIdx.x * 64;
  const int arow = tid >> 2, acol = (tid & 3) << 2;
  const int wrow = tid >> 4, wcol = (tid & 15) << 2;
  float acc[4][4] = {};
  for (int k0 = 0; k0 < K; k0 += 16) {
    const float4 av = *reinterpret_cast<const float4*>(&A[(size_t)(bm + arow) * K + k0 + acol]);
    const float4 wv = *reinterpret_cast<const float4*>(&W[(size_t)(k0 + wrow) * N + bn + wcol]);
    __syncthreads();
    As[acol + 0][arow] = av.x; As[acol + 1][arow] = av.y;
    As[acol + 2][arow] = av.z; As[acol + 3][arow] = av.w;
    *reinterpret_cast<float4*>(&Ws[wrow][wcol]) = wv;
    __syncthreads();
#pragma unroll
    for (int kk = 0; kk < 16; ++kk) {
      const float4 a4 = *reinterpret_cast<const float4*>(&As[kk][ty * 4]);
      const float4 w4 = *reinterpret_cast<const float4*>(&Ws[kk][tx * 4]);
      const float a[4] = {a4.x, a4.y, a4.z, a4.w};
      const float w[4] = {w4.x, w4.y, w4.z, w4.w};
#pragma unroll
      for (int i = 0; i < 4; ++i)
#pragma unroll
        for (int j = 0; j < 4; ++j)
          acc[i][j] = fmaf(a[i], w[j], acc[i][j]);
    }
  }
#pragma unroll
  for (int i = 0; i < 4; ++i) {
    const int row = bm + ty * 4 + i;
#pragma unroll
    for (int j = 0; j < 4; ++j) {
      const int col = bn + tx * 4 + j;
      float v = acc[i][j];
      if (bias) v += bias[col];
      const size_t idx = (size_t)row * N + col;
      if (Cb) Cb[idx] = f2bf(v); else Cf[idx] = v;
    }
  }
}

// ---- MFMA attention: mode0 = heads 4..7 local; mode1 = global all heads ---
__global__ __launch_bounds__(256) void msa_attn_mfma_r9(
    const unsigned short* __restrict__ qsrc, const unsigned short* __restrict__ kvsrc,
    float* __restrict__ out, int mode)
{
  __shared__ __align__(16) unsigned short K_lds[32][40];   // [key][ch]
  __shared__ __align__(16) unsigned short V_lds[32][40];   // [ch][key] (transposed)
  __shared__ __align__(16) unsigned short P_lds[4][16][40]; // per-wave [q][key]

  const int tid = threadIdx.x;
  const int wave = tid >> 6, lane = tid & 63;
  const int q16 = lane & 15, h = lane >> 4;
  const int b = blockIdx.y;

  int head, NTOK, P2, lp, pm1, base;
  if (mode) {
    head = blockIdx.z; NTOK = 1024; P2 = 1024; lp = 0; pm1 = 0; base = 0;
  } else {
    head = 4 + blockIdx.z;
    lp = (head < 6) ? 4 : 5;
    const int p = 1 << lp; pm1 = p - 1;
    NTOK = 4096; P2 = p * p;
    const int patch = (blockIdx.x * 64) >> (2 * lp);   // 64 queries per block: one patch
    const int nbp = 64 >> lp;
    const int hb = patch / nbp, wb = patch - (patch / nbp) * nbp;
    base = ((hb << lp)) * 64 + (wb << lp);
  }
  const int nq = blockIdx.x * 64 + wave * 16 + q16;
  int n;
  if (mode) n = nq;
  else { const int t = nq & (P2 - 1); n = base + ((t >> lp) << 6) + (t & pm1); }

  // Q-frag: 8 bf16, channels 8h..8h+7 (B-operand: col=q16, same k-map as A)
  const bf16x8 qfrag = *reinterpret_cast<const bf16x8*>(
      qsrc + ((size_t)b * NTOK + n) * 256 + head * 32 + 8 * h);

  const float scale = 0.17677669529663687f;  // 32^-0.5
  float m = -3.0e38f, l = 0.f;
  f32x4 o0 = {0.f, 0.f, 0.f, 0.f}, o1 = {0.f, 0.f, 0.f, 0.f};
  const f32x4 zc = {0.f, 0.f, 0.f, 0.f};

  const int skey = (tid & 127) >> 2;   // 0..31
  const int sh = tid & 3;              // 0..3
  const bool isK = tid < 128;

  for (int kc = 0; kc < P2; kc += 32) {
    __syncthreads();
    {
      const int kk = kc + skey;
      const int nk = mode ? kk : base + ((kk >> lp) << 6) + (kk & pm1);
      const unsigned short* src = kvsrc + ((size_t)b * NTOK + nk) * 512 + head * 32
                                + (isK ? 0 : 256) + 8 * sh;
      const bf16x8 v = *reinterpret_cast<const bf16x8*>(src);
      if (isK) {
        *reinterpret_cast<bf16x8*>(&K_lds[skey][8 * sh]) = v;
      } else {
#pragma unroll
        for (int j = 0; j < 8; ++j)
          V_lds[8 * sh + j][skey] = (unsigned short)v[j];
      }
    }
    __syncthreads();

    // S^T tiles: rows=keys, cols=queries
    const bf16x8 k0 = *reinterpret_cast<const bf16x8*>(&K_lds[q16][8 * h]);
    const bf16x8 k1 = *reinterpret_cast<const bf16x8*>(&K_lds[16 + q16][8 * h]);
    const f32x4 st0 = __builtin_amdgcn_mfma_f32_16x16x32_bf16(k0, qfrag, zc, 0, 0, 0);
    const f32x4 st1 = __builtin_amdgcn_mfma_f32_16x16x32_bf16(k1, qfrag, zc, 0, 0, 0);

    float s[8];
#pragma unroll
    for (int i = 0; i < 4; ++i) { s[i] = st0[i] * scale; s[4 + i] = st1[i] * scale; }
    float cmax = s[0];
#pragma unroll
    for (int i = 1; i < 8; ++i) cmax = fmaxf(cmax, s[i]);
    cmax = fmaxf(cmax, __shfl_xor(cmax, 16));
    cmax = fmaxf(cmax, __shfl_xor(cmax, 32));
    const float mnew = fmaxf(m, cmax);
    const float f = __expf(m - mnew);     // first chunk: exp(-huge)=0
    float ps = 0.f;
    unsigned short pb[8];
#pragma unroll
    for (int i = 0; i < 8; ++i) {
      const float pe = __expf(s[i] - mnew);
      ps += pe;
      pb[i] = f2bf(pe);
    }
    l = l * f + ps;
    o0 *= f; o1 *= f;
    m = mnew;

    // P^T to per-wave LDS: lane's keys {4h..4h+3} and {16+4h..16+4h+3} at row q16
    *reinterpret_cast<uint2*>(&P_lds[wave][q16][4 * h]) =
        make_uint2((unsigned)pb[0] | ((unsigned)pb[1] << 16),
                   (unsigned)pb[2] | ((unsigned)pb[3] << 16));
    *reinterpret_cast<uint2*>(&P_lds[wave][q16][16 + 4 * h]) =
        make_uint2((unsigned)pb[4] | ((unsigned)pb[5] << 16),
                   (unsigned)pb[6] | ((unsigned)pb[7] << 16));

    // PV: O^T[ch][q] += V^T * P^T  (keys 8h..8h+7 per lane-group, both operands)
    const bf16x8 pf = *reinterpret_cast<const bf16x8*>(&P_lds[wave][q16][8 * h]);
    const bf16x8 v0 = *reinterpret_cast<const bf16x8*>(&V_lds[q16][8 * h]);
    const bf16x8 v1 = *reinterpret_cast<const bf16x8*>(&V_lds[16 + q16][8 * h]);
    o0 = __builtin_amdgcn_mfma_f32_16x16x32_bf16(v0, pf, o0, 0, 0, 0);
    o1 = __builtin_amdgcn_mfma_f32_16x16x32_bf16(v1, pf, o1, 0, 0, 0);
  }

  l = l + __shfl_xor(l, 16);
  l = l + __shfl_xor(l, 32);
  const float inv = 1.f / l;
  float* dst = out + ((size_t)b * NTOK + nq) * 256 + head * 32;
  float4 w0, w1;
  w0.x = o0[0] * inv; w0.y = o0[1] * inv; w0.z = o0[2] * inv; w0.w = o0[3] * inv;
  w1.x = o1[0] * inv; w1.y = o1[1] * inv; w1.z = o1[2] * inv; w1.w = o1[3] * inv;
  *reinterpret_cast<float4*>(dst + 4 * h) = w0;
  *reinterpret_cast<float4*>(dst + 16 + 4 * h) = w1;
}

// ---- small heads (p=4,8): fp32 register path, bf16 inputs -----------------
__global__ __launch_bounds__(64) void msa_attn_small_r9(
    const unsigned short* __restrict__ xq, const unsigned short* __restrict__ xkv,
    float* __restrict__ out)
{
  const int head = blockIdx.z;                // 0..3
  const int p = (head < 2) ? 4 : 8;
  const int b = blockIdx.y;
  const int nq = blockIdx.x * 64 + threadIdx.x;
  const int P2 = p * p;
  const int patch = nq / P2;
  const int t = nq - patch * P2;
  const int nbp = 64 / p;
  const int hb = patch / nbp, wb = patch - (patch / nbp) * nbp;
  const int n = (hb * p + t / p) * 64 + (wb * p + t - (t / p) * p);

  float qr[32];
  {
    const bf16x8* q8 = reinterpret_cast<const bf16x8*>(
        xq + ((size_t)b * 4096 + n) * 256 + head * 32);
#pragma unroll
    for (int i = 0; i < 4; ++i) {
      const bf16x8 v = q8[i];
#pragma unroll
      for (int j = 0; j < 8; ++j) qr[i * 8 + j] = bf2f((unsigned short)v[j]);
    }
  }
  const float scale = 0.17677669529663687f;
  float m = -3.0e38f, l = 0.f;
  float acc[32] = {};
  const int kbase = (hb * p) * 64 + wb * p;
  for (int kk = 0; kk < P2; ++kk) {
    const int nk = kbase + (kk / p) * 64 + (kk - (kk / p) * p);
    const bf16x8* kv8 = reinterpret_cast<const bf16x8*>(
        xkv + ((size_t)b * 4096 + nk) * 512 + head * 32);
    float s = 0.f;
#pragma unroll
    for (int i = 0; i < 4; ++i) {
      const bf16x8 k8 = kv8[i];
#pragma unroll
      for (int j = 0; j < 8; ++j) s = fmaf(qr[i * 8 + j], bf2f((unsigned short)k8[j]), s);
    }
    s *= scale;
    if (s <= m) {
      const float pe = __expf(s - m);
      l += pe;
#pragma unroll
      for (int i = 0; i < 4; ++i) {
        const bf16x8 v8 = kv8[32 + i];
#pragma unroll
        for (int j = 0; j < 8; ++j)
          acc[i * 8 + j] = fmaf(pe, bf2f((unsigned short)v8[j]), acc[i * 8 + j]);
      }
    } else {
      const float f = __expf(m - s);
      l = fmaf(l, f, 1.f);
#pragma unroll
      for (int i = 0; i < 4; ++i) {
        const bf16x8 v8 = kv8[32 + i];
#pragma unroll
        for (int j = 0; j < 8; ++j)
          acc[i * 8 + j] = fmaf(acc[i * 8 + j], f, bf2f((unsigned short)v8[j]));
      }
      m = s;
    }
  }
  const float inv = 1.f / l;
  float* dst = out + ((size_t)b * 4096 + nq) * 256 + head * 32;
#pragma unroll
  for (int c = 0; c < 32; ++c) dst[c] = acc[c] * inv;
}

// qg_all[b][head][t][c] = mean over patches of q (bf16 in, f32 out)
__global__ __launch_bounds__(256) void msa_qg_reduce_r9(
    const unsigned short* __restrict__ xq, float* __restrict__ qg_all)
{
  const int head = blockIdx.z;
  const int p = (head < 2) ? 4 : (head < 4) ? 8 : (head < 6) ? 16 : 32;
  const int e = blockIdx.x * 256 + threadIdx.x;
  const int b = blockIdx.y;
  const int P2 = p * p;
  if (e >= P2 * 32) return;
  const int t = e >> 5, c = e & 31;
  const int nbp = 64 / p;
  const int hp = t / p, wp = t - (t / p) * p;
  float s = 0.f;
  for (int hb = 0; hb < nbp; ++hb)
    for (int wb = 0; wb < nbp; ++wb) {
      const int n = (hb * p + hp) * 64 + (wb * p + wp);
      s += bf2f(xq[((size_t)b * 4096 + n) * 256 + head * 32 + c]);
    }
  qg_all[((size_t)b * 8 + head) * 32768 + (size_t)t * 32 + c] = s / (float)(nbp * nbp);
}

// bilinear upsample (p x p -> 32 x 32) -> Qg bf16
__global__ __launch_bounds__(256) void msa_qg_upsample_r9(
    const float* __restrict__ qg_all, unsigned short* __restrict__ Qg)
{
  const int head = blockIdx.z;
  const int p = (head < 2) ? 4 : (head < 4) ? 8 : (head < 6) ? 16 : 32;
  const int e = blockIdx.x * 256 + threadIdx.x;
  const int b = blockIdx.y;
  const int mlin = e >> 5, c = e & 31;
  const int mi = mlin >> 5, mj = mlin & 31;
  const float* src = qg_all + ((size_t)b * 8 + head) * 32768;
  float v;
  if (p == 32) {
    v = src[(size_t)mlin * 32 + c];
  } else {
    const float s = (float)p / 32.0f;
    const float xf = (mj + 0.5f) * s - 0.5f;
    const float yf = (mi + 0.5f) * s - 0.5f;
    const float xfl = floorf(xf), yfl = floorf(yf);
    const float fx = xf - xfl, fy = yf - yfl;
    const int x0 = (int)xfl, y0 = (int)yfl;
    const int x0c = max(0, min(p - 1, x0)), x1c = max(0, min(p - 1, x0 + 1));
    const int y0c = max(0, min(p - 1, y0)), y1c = max(0, min(p - 1, y0 + 1));
    const float v00 = src[(size_t)(y0c * p + x0c) * 32 + c];
    const float v01 = src[(size_t)(y0c * p + x1c) * 32 + c];
    const float v10 = src[(size_t)(y1c * p + x0c) * 32 + c];
    const float v11 = src[(size_t)(y1c * p + x1c) * 32 + c];
    v = (1.f - fy) * ((1.f - fx) * v00 + fx * v01)
      + fy * ((1.f - fx) * v10 + fx * v11);
  }
  Qg[((size_t)b * 1024 + mlin) * 256 + head * 32 + c] = f2bf(v);
}

// 2x2 avg pool over the n'-grid -> pooled [B,1024,256] f32
__global__ __launch_bounds__(256) void msa_pool_r9(
    const float* __restrict__ attn, float* __restrict__ pooled)
{
  const int c = threadIdx.x;
  const int mlin = blockIdx.x;
  const int b = blockIdx.y;
  const int mi = mlin >> 5, mj = mlin & 31;
  const size_t base = (size_t)b * 4096;
  const int r0 = mi * 2, q0 = mj * 2;
  float s = attn[(base + (r0 * 64 + q0)) * 256 + c]
          + attn[(base + (r0 * 64 + q0 + 1)) * 256 + c]
          + attn[(base + ((r0 + 1) * 64 + q0)) * 256 + c]
          + attn[(base + ((r0 + 1) * 64 + q0 + 1)) * 256 + c];
  pooled[((size_t)b * 1024 + mlin) * 256 + c] = s * 0.25f;
}

// attn[n] += bilinear_upsample(gl, 32->64)[n]
__global__ __launch_bounds__(256) void msa_blend_r9(
    const float* __restrict__ gl, float* __restrict__ attn)
{
  const int c = threadIdx.x;
  const int n = blockIdx.x;
  const int b = blockIdx.y;
  const int hh = n >> 6, w = n & 63;
  const float xf = (w + 0.5f) * 0.5f - 0.5f;
  const float yf = (hh + 0.5f) * 0.5f - 0.5f;
  const float xfl = floorf(xf), yfl = floorf(yf);
  const float fx = xf - xfl, fy = yf - yfl;
  const int x0 = (int)xfl, y0 = (int)yfl;
  const int x0c = max(0, min(31, x0)), x1c = max(0, min(31, x0 + 1));
  const int y0c = max(0, min(31, y0)), y1c = max(0, min(31, y0 + 1));
  const float* g = gl + (size_t)b * 1024 * 256;
  const float v00 = g[(size_t)(y0c * 32 + x0c) * 256 + c];
  const float v01 = g[(size_t)(y0c * 32 + x1c) * 256 + c];
  const float v10 = g[(size_t)(y1c * 32 + x0c) * 256 + c];
  const float v11 = g[(size_t)(y1c * 32 + x1c) * 256 + c];
  const float v = (1.f - fy) * ((1.f - fx) * v00 + fx * v01)
                + fy * ((1.f - fx) * v10 + fx * v11);
  attn[((size_t)b * 4096 + n) * 256 + c] += v;
}

extern "C" void kernel_launch(void* const* d_in, const int* in_sizes, int n_in,
                              void* d_out, int out_size, void* d_ws, size_t ws_size,
                              hipStream_t stream)
{
  const float* x     = (const float*)d_in[0];
  const float* Wq    = (const float*)d_in[1];
  const float* Wkv   = (const float*)d_in[2];
  const float* Wlkv  = (const float*)d_in[3];
  const float* Wproj = (const float*)d_in[4];
  const float* bproj = (const float*)d_in[5];

  char* ws = (char*)d_ws;
  unsigned short* xq  = (unsigned short*)(ws + 0);            // [32768,256] bf16
  unsigned short* xkv = (unsigned short*)(ws + 16777216ull);  // [32768,512] bf16
  float* attn   = (float*)(ws + 50331648ull);                 // [32768,256] f32
  unsigned short* Qg  = (unsigned short*)(ws + 83886080ull);  // [8192,256] bf16
  float* qg_all = (float*)(ws + 88080384ull);                 // [8,8,1024,32] f32
  float* pooled = (float*)(ws + 0);                           // over dead xq
  float* gl     = (float*)(ws + 8388608ull);                  // over xq tail
  unsigned short* kv2 = (unsigned short*)(ws + 16777216ull);  // over dead xkv

  // 1) projections (fp32 compute, bf16 store)
  msa_gemm_r9<<<dim3(4, 512), 256, 0, stream>>>(x, Wq, nullptr, nullptr, xq, 256, 256);
  msa_gemm_r9<<<dim3(8, 512), 256, 0, stream>>>(x, Wkv, nullptr, nullptr, xkv, 256, 512);

  // 2) global-query means + bilinear upsample (Qg bf16)
  msa_qg_reduce_r9<<<dim3(128, 8, 8), 256, 0, stream>>>(xq, qg_all);
  msa_qg_upsample_r9<<<dim3(128, 8, 8), 256, 0, stream>>>(qg_all, Qg);

  // 3) local windowed attention
  msa_attn_small_r9<<<dim3(64, 8, 4), 64, 0, stream>>>(xq, xkv, attn);
  msa_attn_mfma_r9<<<dim3(64, 8, 4), 256, 0, stream>>>(xq, xkv, attn, 0);

  // 4) pool + kv2 projection (bf16 store)
  msa_pool_r9<<<dim3(1024, 8), 256, 0, stream>>>(attn, pooled);
  msa_gemm_r9<<<dim3(8, 128), 256, 0, stream>>>(pooled, Wlkv, nullptr, nullptr, kv2, 256, 512);

  // 5) global cross-attention (MFMA)
  msa_attn_mfma_r9<<<dim3(16, 8, 8), 256, 0, stream>>>(Qg, kv2, gl, 1);

  // 6) blend + final projection (fp32 out)
  msa_blend_r9<<<dim3(4096, 8), 256, 0, stream>>>(gl, attn);
  msa_gemm_r9<<<dim3(4, 512), 256, 0, stream>>>(attn, Wproj, bproj, (float*)d_out, nullptr, 256, 256);

  (void)in_sizes; (void)n_in; (void)out_size; (void)ws_size;
}

// Round 10
// 371.368 us; speedup vs baseline: 32.3054x; 1.5119x over previous
//
#include <hip/hip_runtime.h>
#include <math.h>

// ---------------------------------------------------------------------------
// ROUND 10: everything heavy on MFMA bf16.
//  - GEMMs: 128x128 block tile, 4 waves, 64x64/wave, BK=32, LDS stride-40 pad.
//    A staged fp32->bf16 in-register (or bf16 direct); B from pre-transposed
//    bf16 weights Wt[n][k].
//  - attention: r9 MFMA structure; attn buffer now bf16.
//  - fragment maps validated on HW by r9: A row=l&15 k=(l>>4)*8+j;
//    B col=l&15; C col=l&15 row=(l>>4)*4+reg.
// ---------------------------------------------------------------------------

typedef __attribute__((ext_vector_type(8))) short bf16x8;
typedef __attribute__((ext_vector_type(4))) float f32x4;

__device__ inline float bf2f(unsigned short u) {
  union { unsigned int i; float f; } v; v.i = ((unsigned int)u) << 16; return v.f;
}
__device__ inline unsigned short f2bf(float x) {
  union { float f; unsigned int i; } v; v.f = x;
  return (unsigned short)((v.i + 0x7FFFu + ((v.i >> 16) & 1u)) >> 16);
}

// ---- weight cast+transpose: Wt[n][k] = bf16(W[k][n]) ----------------------
__global__ __launch_bounds__(256) void msa_wcast_r10(
    const float* __restrict__ W, unsigned short* __restrict__ Wt, int K, int N)
{
  const int id = blockIdx.x * 256 + threadIdx.x;
  if (id >= K * N) return;
  const int k = id / N, n = id - (id / N) * N;
  Wt[(size_t)n * K + k] = f2bf(W[id]);
}

// ---- MFMA GEMM: C[M,N] = A[M,256] @ W[256,N] (+bias) ----------------------
// A from Af (fp32) or Ab (bf16); W from Wt[n][k] bf16; C to Cf (fp32) or Cb.
// grid = (N/128, M/128), block = 256.
__global__ __launch_bounds__(256) void msa_gemm_mfma_r10(
    const float* __restrict__ Af, const unsigned short* __restrict__ Ab,
    const unsigned short* __restrict__ Wt, const float* __restrict__ bias,
    float* __restrict__ Cf, unsigned short* __restrict__ Cb, int K, int N)
{
  __shared__ __align__(16) unsigned short A_lds[128][40];
  __shared__ __align__(16) unsigned short B_lds[128][40];

  const int tid = threadIdx.x;
  const int wave = tid >> 6, lane = tid & 63;
  const int l15 = lane & 15, g = lane >> 4;
  const int bm = blockIdx.y * 128, bn = blockIdx.x * 128;
  const int wr = (wave >> 1) * 64, wc = (wave & 1) * 64;

  f32x4 acc[4][4] = {};

  for (int k0 = 0; k0 < K; k0 += 32) {
    __syncthreads();
#pragma unroll
    for (int s = 0; s < 2; ++s) {
      const int id = tid + s * 256;          // 0..511
      const int row = id >> 2, sg = (id & 3) << 3;
      if (Ab) {
        *reinterpret_cast<bf16x8*>(&A_lds[row][sg]) =
            *reinterpret_cast<const bf16x8*>(&Ab[(size_t)(bm + row) * K + k0 + sg]);
      } else {
        const float4 v0 = *reinterpret_cast<const float4*>(&Af[(size_t)(bm + row) * K + k0 + sg]);
        const float4 v1 = *reinterpret_cast<const float4*>(&Af[(size_t)(bm + row) * K + k0 + sg + 4]);
        bf16x8 o;
        o[0] = (short)f2bf(v0.x); o[1] = (short)f2bf(v0.y);
        o[2] = (short)f2bf(v0.z); o[3] = (short)f2bf(v0.w);
        o[4] = (short)f2bf(v1.x); o[5] = (short)f2bf(v1.y);
        o[6] = (short)f2bf(v1.z); o[7] = (short)f2bf(v1.w);
        *reinterpret_cast<bf16x8*>(&A_lds[row][sg]) = o;
      }
      *reinterpret_cast<bf16x8*>(&B_lds[row][sg]) =
          *reinterpret_cast<const bf16x8*>(&Wt[(size_t)(bn + row) * K + k0 + sg]);
    }
    __syncthreads();

    bf16x8 a_frag[4], b_frag[4];
#pragma unroll
    for (int mi = 0; mi < 4; ++mi)
      a_frag[mi] = *reinterpret_cast<const bf16x8*>(&A_lds[wr + mi * 16 + l15][g << 3]);
#pragma unroll
    for (int ni = 0; ni < 4; ++ni)
      b_frag[ni] = *reinterpret_cast<const bf16x8*>(&B_lds[wc + ni * 16 + l15][g << 3]);
#pragma unroll
    for (int mi = 0; mi < 4; ++mi)
#pragma unroll
      for (int ni = 0; ni < 4; ++ni)
        acc[mi][ni] = __builtin_amdgcn_mfma_f32_16x16x32_bf16(
            a_frag[mi], b_frag[ni], acc[mi][ni], 0, 0, 0);
  }

#pragma unroll
  for (int mi = 0; mi < 4; ++mi)
#pragma unroll
    for (int ni = 0; ni < 4; ++ni) {
      const int col = bn + wc + ni * 16 + l15;
#pragma unroll
      for (int i = 0; i < 4; ++i) {
        const int row = bm + wr + mi * 16 + g * 4 + i;
        float v = acc[mi][ni][i];
        if (bias) v += bias[col];
        const size_t idx = (size_t)row * N + col;
        if (Cb) Cb[idx] = f2bf(v); else Cf[idx] = v;
      }
    }
}

// ---- MFMA attention: mode0 = heads 4..7 local (bf16 out); mode1 = global --
__global__ __launch_bounds__(256) void msa_attn_mfma_r10(
    const unsigned short* __restrict__ qsrc, const unsigned short* __restrict__ kvsrc,
    float* __restrict__ outf, unsigned short* __restrict__ outb, int mode)
{
  __shared__ __align__(16) unsigned short K_lds[32][40];
  __shared__ __align__(16) unsigned short V_lds[32][40];
  __shared__ __align__(16) unsigned short P_lds[4][16][40];

  const int tid = threadIdx.x;
  const int wave = tid >> 6, lane = tid & 63;
  const int q16 = lane & 15, h = lane >> 4;
  const int b = blockIdx.y;

  int head, NTOK, P2, lp, pm1, base;
  if (mode) {
    head = blockIdx.z; NTOK = 1024; P2 = 1024; lp = 0; pm1 = 0; base = 0;
  } else {
    head = 4 + blockIdx.z;
    lp = (head < 6) ? 4 : 5;
    const int p = 1 << lp; pm1 = p - 1;
    NTOK = 4096; P2 = p * p;
    const int patch = (blockIdx.x * 64) >> (2 * lp);
    const int nbp = 64 >> lp;
    const int hb = patch / nbp, wb = patch - (patch / nbp) * nbp;
    base = ((hb << lp)) * 64 + (wb << lp);
  }
  const int nq = blockIdx.x * 64 + wave * 16 + q16;
  int n;
  if (mode) n = nq;
  else { const int t = nq & (P2 - 1); n = base + ((t >> lp) << 6) + (t & pm1); }

  const bf16x8 qfrag = *reinterpret_cast<const bf16x8*>(
      qsrc + ((size_t)b * NTOK + n) * 256 + head * 32 + 8 * h);

  const float scale = 0.17677669529663687f;
  float m = -3.0e38f, l = 0.f;
  f32x4 o0 = {0.f, 0.f, 0.f, 0.f}, o1 = {0.f, 0.f, 0.f, 0.f};
  const f32x4 zc = {0.f, 0.f, 0.f, 0.f};

  const int skey = (tid & 127) >> 2;
  const int sh = tid & 3;
  const bool isK = tid < 128;

  for (int kc = 0; kc < P2; kc += 32) {
    __syncthreads();
    {
      const int kk = kc + skey;
      const int nk = mode ? kk : base + ((kk >> lp) << 6) + (kk & pm1);
      const unsigned short* src = kvsrc + ((size_t)b * NTOK + nk) * 512 + head * 32
                                + (isK ? 0 : 256) + 8 * sh;
      const bf16x8 v = *reinterpret_cast<const bf16x8*>(src);
      if (isK) {
        *reinterpret_cast<bf16x8*>(&K_lds[skey][8 * sh]) = v;
      } else {
#pragma unroll
        for (int j = 0; j < 8; ++j)
          V_lds[8 * sh + j][skey] = (unsigned short)v[j];
      }
    }
    __syncthreads();

    const bf16x8 k0 = *reinterpret_cast<const bf16x8*>(&K_lds[q16][8 * h]);
    const bf16x8 k1 = *reinterpret_cast<const bf16x8*>(&K_lds[16 + q16][8 * h]);
    const f32x4 st0 = __builtin_amdgcn_mfma_f32_16x16x32_bf16(k0, qfrag, zc, 0, 0, 0);
    const f32x4 st1 = __builtin_amdgcn_mfma_f32_16x16x32_bf16(k1, qfrag, zc, 0, 0, 0);

    float s[8];
#pragma unroll
    for (int i = 0; i < 4; ++i) { s[i] = st0[i] * scale; s[4 + i] = st1[i] * scale; }
    float cmax = s[0];
#pragma unroll
    for (int i = 1; i < 8; ++i) cmax = fmaxf(cmax, s[i]);
    cmax = fmaxf(cmax, __shfl_xor(cmax, 16));
    cmax = fmaxf(cmax, __shfl_xor(cmax, 32));
    const float mnew = fmaxf(m, cmax);
    const float f = __expf(m - mnew);
    float ps = 0.f;
    unsigned short pb[8];
#pragma unroll
    for (int i = 0; i < 8; ++i) {
      const float pe = __expf(s[i] - mnew);
      ps += pe;
      pb[i] = f2bf(pe);
    }
    l = l * f + ps;
    o0 *= f; o1 *= f;
    m = mnew;

    *reinterpret_cast<uint2*>(&P_lds[wave][q16][4 * h]) =
        make_uint2((unsigned)pb[0] | ((unsigned)pb[1] << 16),
                   (unsigned)pb[2] | ((unsigned)pb[3] << 16));
    *reinterpret_cast<uint2*>(&P_lds[wave][q16][16 + 4 * h]) =
        make_uint2((unsigned)pb[4] | ((unsigned)pb[5] << 16),
                   (unsigned)pb[6] | ((unsigned)pb[7] << 16));

    const bf16x8 pf = *reinterpret_cast<const bf16x8*>(&P_lds[wave][q16][8 * h]);
    const bf16x8 v0 = *reinterpret_cast<const bf16x8*>(&V_lds[q16][8 * h]);
    const bf16x8 v1 = *reinterpret_cast<const bf16x8*>(&V_lds[16 + q16][8 * h]);
    o0 = __builtin_amdgcn_mfma_f32_16x16x32_bf16(v0, pf, o0, 0, 0, 0);
    o1 = __builtin_amdgcn_mfma_f32_16x16x32_bf16(v1, pf, o1, 0, 0, 0);
  }

  l = l + __shfl_xor(l, 16);
  l = l + __shfl_xor(l, 32);
  const float inv = 1.f / l;
  const size_t obase = ((size_t)b * NTOK + nq) * 256 + head * 32;
  if (mode) {
    float* dst = outf + obase;
    float4 w0, w1;
    w0.x = o0[0] * inv; w0.y = o0[1] * inv; w0.z = o0[2] * inv; w0.w = o0[3] * inv;
    w1.x = o1[0] * inv; w1.y = o1[1] * inv; w1.z = o1[2] * inv; w1.w = o1[3] * inv;
    *reinterpret_cast<float4*>(dst + 4 * h) = w0;
    *reinterpret_cast<float4*>(dst + 16 + 4 * h) = w1;
  } else {
    unsigned short* dst = outb + obase;
    uint2 w0, w1;
    w0.x = (unsigned)f2bf(o0[0] * inv) | ((unsigned)f2bf(o0[1] * inv) << 16);
    w0.y = (unsigned)f2bf(o0[2] * inv) | ((unsigned)f2bf(o0[3] * inv) << 16);
    w1.x = (unsigned)f2bf(o1[0] * inv) | ((unsigned)f2bf(o1[1] * inv) << 16);
    w1.y = (unsigned)f2bf(o1[2] * inv) | ((unsigned)f2bf(o1[3] * inv) << 16);
    *reinterpret_cast<uint2*>(dst + 4 * h) = w0;
    *reinterpret_cast<uint2*>(dst + 16 + 4 * h) = w1;
  }
}

// ---- small heads (p=4,8): fp32 register path, bf16 in, bf16 out -----------
__global__ __launch_bounds__(64) void msa_attn_small_r10(
    const unsigned short* __restrict__ xq, const unsigned short* __restrict__ xkv,
    unsigned short* __restrict__ out)
{
  const int head = blockIdx.z;
  const int p = (head < 2) ? 4 : 8;
  const int b = blockIdx.y;
  const int nq = blockIdx.x * 64 + threadIdx.x;
  const int P2 = p * p;
  const int patch = nq / P2;
  const int t = nq - patch * P2;
  const int nbp = 64 / p;
  const int hb = patch / nbp, wb = patch - (patch / nbp) * nbp;
  const int n = (hb * p + t / p) * 64 + (wb * p + t - (t / p) * p);

  float qr[32];
  {
    const bf16x8* q8 = reinterpret_cast<const bf16x8*>(
        xq + ((size_t)b * 4096 + n) * 256 + head * 32);
#pragma unroll
    for (int i = 0; i < 4; ++i) {
      const bf16x8 v = q8[i];
#pragma unroll
      for (int j = 0; j < 8; ++j) qr[i * 8 + j] = bf2f((unsigned short)v[j]);
    }
  }
  const float scale = 0.17677669529663687f;
  float m = -3.0e38f, l = 0.f;
  float acc[32] = {};
  const int kbase = (hb * p) * 64 + wb * p;
  for (int kk = 0; kk < P2; ++kk) {
    const int nk = kbase + (kk / p) * 64 + (kk - (kk / p) * p);
    const bf16x8* kv8 = reinterpret_cast<const bf16x8*>(
        xkv + ((size_t)b * 4096 + nk) * 512 + head * 32);
    float s = 0.f;
#pragma unroll
    for (int i = 0; i < 4; ++i) {
      const bf16x8 k8 = kv8[i];
#pragma unroll
      for (int j = 0; j < 8; ++j) s = fmaf(qr[i * 8 + j], bf2f((unsigned short)k8[j]), s);
    }
    s *= scale;
    if (s <= m) {
      const float pe = __expf(s - m);
      l += pe;
#pragma unroll
      for (int i = 0; i < 4; ++i) {
        const bf16x8 v8 = kv8[32 + i];
#pragma unroll
        for (int j = 0; j < 8; ++j)
          acc[i * 8 + j] = fmaf(pe, bf2f((unsigned short)v8[j]), acc[i * 8 + j]);
      }
    } else {
      const float f = __expf(m - s);
      l = fmaf(l, f, 1.f);
#pragma unroll
      for (int i = 0; i < 4; ++i) {
        const bf16x8 v8 = kv8[32 + i];
#pragma unroll
        for (int j = 0; j < 8; ++j)
          acc[i * 8 + j] = fmaf(acc[i * 8 + j], f, bf2f((unsigned short)v8[j]));
      }
      m = s;
    }
  }
  const float inv = 1.f / l;
  unsigned short* dst = out + ((size_t)b * 4096 + nq) * 256 + head * 32;
#pragma unroll
  for (int c = 0; c < 32; ++c) dst[c] = f2bf(acc[c] * inv);
}

// qg_all[b][head][t][c] = mean over patches of q (bf16 in, f32 out)
__global__ __launch_bounds__(256) void msa_qg_reduce_r10(
    const unsigned short* __restrict__ xq, float* __restrict__ qg_all)
{
  const int head = blockIdx.z;
  const int p = (head < 2) ? 4 : (head < 4) ? 8 : (head < 6) ? 16 : 32;
  const int e = blockIdx.x * 256 + threadIdx.x;
  const int b = blockIdx.y;
  const int P2 = p * p;
  if (e >= P2 * 32) return;
  const int t = e >> 5, c = e & 31;
  const int nbp = 64 / p;
  const int hp = t / p, wp = t - (t / p) * p;
  float s = 0.f;
  for (int hb = 0; hb < nbp; ++hb)
    for (int wb = 0; wb < nbp; ++wb) {
      const int n = (hb * p + hp) * 64 + (wb * p + wp);
      s += bf2f(xq[((size_t)b * 4096 + n) * 256 + head * 32 + c]);
    }
  qg_all[((size_t)b * 8 + head) * 32768 + (size_t)t * 32 + c] = s / (float)(nbp * nbp);
}

// bilinear upsample (p x p -> 32 x 32) -> Qg bf16
__global__ __launch_bounds__(256) void msa_qg_upsample_r10(
    const float* __restrict__ qg_all, unsigned short* __restrict__ Qg)
{
  const int head = blockIdx.z;
  const int p = (head < 2) ? 4 : (head < 4) ? 8 : (head < 6) ? 16 : 32;
  const int e = blockIdx.x * 256 + threadIdx.x;
  const int b = blockIdx.y;
  const int mlin = e >> 5, c = e & 31;
  const int mi = mlin >> 5, mj = mlin & 31;
  const float* src = qg_all + ((size_t)b * 8 + head) * 32768;
  float v;
  if (p == 32) {
    v = src[(size_t)mlin * 32 + c];
  } else {
    const float s = (float)p / 32.0f;
    const float xf = (mj + 0.5f) * s - 0.5f;
    const float yf = (mi + 0.5f) * s - 0.5f;
    const float xfl = floorf(xf), yfl = floorf(yf);
    const float fx = xf - xfl, fy = yf - yfl;
    const int x0 = (int)xfl, y0 = (int)yfl;
    const int x0c = max(0, min(p - 1, x0)), x1c = max(0, min(p - 1, x0 + 1));
    const int y0c = max(0, min(p - 1, y0)), y1c = max(0, min(p - 1, y0 + 1));
    const float v00 = src[(size_t)(y0c * p + x0c) * 32 + c];
    const float v01 = src[(size_t)(y0c * p + x1c) * 32 + c];
    const float v10 = src[(size_t)(y1c * p + x0c) * 32 + c];
    const float v11 = src[(size_t)(y1c * p + x1c) * 32 + c];
    v = (1.f - fy) * ((1.f - fx) * v00 + fx * v01)
      + fy * ((1.f - fx) * v10 + fx * v11);
  }
  Qg[((size_t)b * 1024 + mlin) * 256 + head * 32 + c] = f2bf(v);
}

// 2x2 avg pool over the n'-grid -> pooled [B,1024,256] bf16
__global__ __launch_bounds__(256) void msa_pool_r10(
    const unsigned short* __restrict__ attn, unsigned short* __restrict__ pooled)
{
  const int c = threadIdx.x;
  const int mlin = blockIdx.x;
  const int b = blockIdx.y;
  const int mi = mlin >> 5, mj = mlin & 31;
  const size_t base = (size_t)b * 4096;
  const int r0 = mi * 2, q0 = mj * 2;
  float s = bf2f(attn[(base + (r0 * 64 + q0)) * 256 + c])
          + bf2f(attn[(base + (r0 * 64 + q0 + 1)) * 256 + c])
          + bf2f(attn[(base + ((r0 + 1) * 64 + q0)) * 256 + c])
          + bf2f(attn[(base + ((r0 + 1) * 64 + q0 + 1)) * 256 + c]);
  pooled[((size_t)b * 1024 + mlin) * 256 + c] = f2bf(s * 0.25f);
}

// attn[n] = bf16( attn[n] + bilinear_upsample(gl, 32->64)[n] )
__global__ __launch_bounds__(256) void msa_blend_r10(
    const float* __restrict__ gl, unsigned short* __restrict__ attn)
{
  const int c = threadIdx.x;
  const int n = blockIdx.x;
  const int b = blockIdx.y;
  const int hh = n >> 6, w = n & 63;
  const float xf = (w + 0.5f) * 0.5f - 0.5f;
  const float yf = (hh + 0.5f) * 0.5f - 0.5f;
  const float xfl = floorf(xf), yfl = floorf(yf);
  const float fx = xf - xfl, fy = yf - yfl;
  const int x0 = (int)xfl, y0 = (int)yfl;
  const int x0c = max(0, min(31, x0)), x1c = max(0, min(31, x0 + 1));
  const int y0c = max(0, min(31, y0)), y1c = max(0, min(31, y0 + 1));
  const float* g = gl + (size_t)b * 1024 * 256;
  const float v00 = g[(size_t)(y0c * 32 + x0c) * 256 + c];
  const float v01 = g[(size_t)(y0c * 32 + x1c) * 256 + c];
  const float v10 = g[(size_t)(y1c * 32 + x0c) * 256 + c];
  const float v11 = g[(size_t)(y1c * 32 + x1c) * 256 + c];
  const float v = (1.f - fy) * ((1.f - fx) * v00 + fx * v01)
                + fy * ((1.f - fx) * v10 + fx * v11);
  const size_t idx = ((size_t)b * 4096 + n) * 256 + c;
  attn[idx] = f2bf(bf2f(attn[idx]) + v);
}

extern "C" void kernel_launch(void* const* d_in, const int* in_sizes, int n_in,
                              void* d_out, int out_size, void* d_ws, size_t ws_size,
                              hipStream_t stream)
{
  const float* x     = (const float*)d_in[0];
  const float* Wq    = (const float*)d_in[1];
  const float* Wkv   = (const float*)d_in[2];
  const float* Wlkv  = (const float*)d_in[3];
  const float* Wproj = (const float*)d_in[4];
  const float* bproj = (const float*)d_in[5];

  char* ws = (char*)d_ws;
  unsigned short* xq    = (unsigned short*)(ws + 0);            // [32768,256] bf16
  unsigned short* xkv   = (unsigned short*)(ws + 16777216ull);  // [32768,512] bf16
  unsigned short* attnb = (unsigned short*)(ws + 50331648ull);  // [32768,256] bf16
  unsigned short* Qg    = (unsigned short*)(ws + 67108864ull);  // [8192,256] bf16
  float* qg_all = (float*)(ws + 71303168ull);                   // [8,8,1024,32] f32
  unsigned short* Wqt   = (unsigned short*)(ws + 79691776ull);  // [256,256] bf16
  unsigned short* Wkvt  = (unsigned short*)(ws + 79822848ull);  // [512,256] bf16
  unsigned short* Wlkvt = (unsigned short*)(ws + 80084992ull);  // [512,256] bf16
  unsigned short* Wprjt = (unsigned short*)(ws + 80347136ull);  // [256,256] bf16
  float* gl     = (float*)(ws + 80478208ull);                   // [8192,256] f32
  unsigned short* pooled = (unsigned short*)(ws + 0);           // over dead xq
  unsigned short* kv2    = (unsigned short*)(ws + 16777216ull); // over dead xkv

  // 0) weight casts (tiny)
  msa_wcast_r10<<<dim3(256), 256, 0, stream>>>(Wq, Wqt, 256, 256);
  msa_wcast_r10<<<dim3(512), 256, 0, stream>>>(Wkv, Wkvt, 256, 512);
  msa_wcast_r10<<<dim3(512), 256, 0, stream>>>(Wlkv, Wlkvt, 256, 512);
  msa_wcast_r10<<<dim3(256), 256, 0, stream>>>(Wproj, Wprjt, 256, 256);

  // 1) projections (MFMA, bf16 store)
  msa_gemm_mfma_r10<<<dim3(2, 256), 256, 0, stream>>>(x, nullptr, Wqt, nullptr, nullptr, xq, 256, 256);
  msa_gemm_mfma_r10<<<dim3(4, 256), 256, 0, stream>>>(x, nullptr, Wkvt, nullptr, nullptr, xkv, 256, 512);

  // 2) global-query means + bilinear upsample
  msa_qg_reduce_r10<<<dim3(128, 8, 8), 256, 0, stream>>>(xq, qg_all);
  msa_qg_upsample_r10<<<dim3(128, 8, 8), 256, 0, stream>>>(qg_all, Qg);

  // 3) local windowed attention (bf16 out)
  msa_attn_small_r10<<<dim3(64, 8, 4), 64, 0, stream>>>(xq, xkv, attnb);
  msa_attn_mfma_r10<<<dim3(64, 8, 4), 256, 0, stream>>>(xq, xkv, nullptr, attnb, 0);

  // 4) pool + kv2 projection (MFMA)
  msa_pool_r10<<<dim3(1024, 8), 256, 0, stream>>>(attnb, pooled);
  msa_gemm_mfma_r10<<<dim3(4, 64), 256, 0, stream>>>(nullptr, pooled, Wlkvt, nullptr, nullptr, kv2, 256, 512);

  // 5) global cross-attention (f32 out to gl)
  msa_attn_mfma_r10<<<dim3(16, 8, 8), 256, 0, stream>>>(Qg, kv2, gl, nullptr, 1);

  // 6) blend + final projection (MFMA, fp32 out + bias)
  msa_blend_r10<<<dim3(4096, 8), 256, 0, stream>>>(gl, attnb);
  msa_gemm_mfma_r10<<<dim3(2, 256), 256, 0, stream>>>(nullptr, attnb, Wprjt, bproj, (float*)d_out, nullptr, 256, 256);

  (void)in_sizes; (void)n_in; (void)out_size; (void)ws_size;
}

// Round 11
// 282.235 us; speedup vs baseline: 42.5079x; 1.3158x over previous
//
#include <hip/hip_runtime.h>
#include <math.h>

// ---------------------------------------------------------------------------
// ROUND 11:
//  - qg_reduce: R-way parallel reduction (R=8 for p<=8), coalesced, LDS tree
//  - fused QKV projection: one GEMM N=768 into xqkv[32768][768] (q|k|v)
//  - weight casts fused into one kernel
//  - attention/GEMM structure from r10 (validated), strides parameterized
// ---------------------------------------------------------------------------

typedef __attribute__((ext_vector_type(8))) short bf16x8;
typedef __attribute__((ext_vector_type(4))) float f32x4;

__device__ inline float bf2f(unsigned short u) {
  union { unsigned int i; float f; } v; v.i = ((unsigned int)u) << 16; return v.f;
}
__device__ inline unsigned short f2bf(float x) {
  union { float f; unsigned int i; } v; v.f = x;
  return (unsigned short)((v.i + 0x7FFFu + ((v.i >> 16) & 1u)) >> 16);
}

// ---- fused weight cast+transpose ------------------------------------------
// Wqkvt[768][256]: rows 0..255 = Wq cols, rows 256..767 = Wkv cols (k|v)
// Wlkvt[512][256], Wprjt[256][256]
__global__ __launch_bounds__(256) void msa_wcast_r11(
    const float* __restrict__ Wq, const float* __restrict__ Wkv,
    const float* __restrict__ Wlkv, const float* __restrict__ Wproj,
    unsigned short* __restrict__ Wqkvt, unsigned short* __restrict__ Wlkvt,
    unsigned short* __restrict__ Wprjt)
{
  const int id = blockIdx.x * 256 + threadIdx.x;
  if (id < 196608) {                       // Wqkvt
    const int r = id >> 8, k = id & 255;
    const float v = (r < 256) ? Wq[(size_t)k * 256 + r] : Wkv[(size_t)k * 512 + (r - 256)];
    Wqkvt[id] = f2bf(v);
  } else if (id < 327680) {                // Wlkvt
    const int j = id - 196608;
    const int n = j >> 8, k = j & 255;
    Wlkvt[j] = f2bf(Wlkv[(size_t)k * 512 + n]);
  } else if (id < 393216) {                // Wprjt
    const int j = id - 327680;
    const int n = j >> 8, k = j & 255;
    Wprjt[j] = f2bf(Wproj[(size_t)k * 256 + n]);
  }
}

// ---- MFMA GEMM: C[M,N] = A[M,256] @ W[256,N] (+bias) ----------------------
__global__ __launch_bounds__(256) void msa_gemm_mfma_r11(
    const float* __restrict__ Af, const unsigned short* __restrict__ Ab,
    const unsigned short* __restrict__ Wt, const float* __restrict__ bias,
    float* __restrict__ Cf, unsigned short* __restrict__ Cb, int K, int N)
{
  __shared__ __align__(16) unsigned short A_lds[128][40];
  __shared__ __align__(16) unsigned short B_lds[128][40];

  const int tid = threadIdx.x;
  const int wave = tid >> 6, lane = tid & 63;
  const int l15 = lane & 15, g = lane >> 4;
  const int bm = blockIdx.y * 128, bn = blockIdx.x * 128;
  const int wr = (wave >> 1) * 64, wc = (wave & 1) * 64;

  f32x4 acc[4][4] = {};

  for (int k0 = 0; k0 < K; k0 += 32) {
    __syncthreads();
#pragma unroll
    for (int s = 0; s < 2; ++s) {
      const int id = tid + s * 256;
      const int row = id >> 2, sg = (id & 3) << 3;
      if (Ab) {
        *reinterpret_cast<bf16x8*>(&A_lds[row][sg]) =
            *reinterpret_cast<const bf16x8*>(&Ab[(size_t)(bm + row) * K + k0 + sg]);
      } else {
        const float4 v0 = *reinterpret_cast<const float4*>(&Af[(size_t)(bm + row) * K + k0 + sg]);
        const float4 v1 = *reinterpret_cast<const float4*>(&Af[(size_t)(bm + row) * K + k0 + sg + 4]);
        bf16x8 o;
        o[0] = (short)f2bf(v0.x); o[1] = (short)f2bf(v0.y);
        o[2] = (short)f2bf(v0.z); o[3] = (short)f2bf(v0.w);
        o[4] = (short)f2bf(v1.x); o[5] = (short)f2bf(v1.y);
        o[6] = (short)f2bf(v1.z); o[7] = (short)f2bf(v1.w);
        *reinterpret_cast<bf16x8*>(&A_lds[row][sg]) = o;
      }
      *reinterpret_cast<bf16x8*>(&B_lds[row][sg]) =
          *reinterpret_cast<const bf16x8*>(&Wt[(size_t)(bn + row) * K + k0 + sg]);
    }
    __syncthreads();

    bf16x8 a_frag[4], b_frag[4];
#pragma unroll
    for (int mi = 0; mi < 4; ++mi)
      a_frag[mi] = *reinterpret_cast<const bf16x8*>(&A_lds[wr + mi * 16 + l15][g << 3]);
#pragma unroll
    for (int ni = 0; ni < 4; ++ni)
      b_frag[ni] = *reinterpret_cast<const bf16x8*>(&B_lds[wc + ni * 16 + l15][g << 3]);
#pragma unroll
    for (int mi = 0; mi < 4; ++mi)
#pragma unroll
      for (int ni = 0; ni < 4; ++ni)
        acc[mi][ni] = __builtin_amdgcn_mfma_f32_16x16x32_bf16(
            a_frag[mi], b_frag[ni], acc[mi][ni], 0, 0, 0);
  }

#pragma unroll
  for (int mi = 0; mi < 4; ++mi)
#pragma unroll
    for (int ni = 0; ni < 4; ++ni) {
      const int col = bn + wc + ni * 16 + l15;
#pragma unroll
      for (int i = 0; i < 4; ++i) {
        const int row = bm + wr + mi * 16 + g * 4 + i;
        float v = acc[mi][ni][i];
        if (bias) v += bias[col];
        const size_t idx = (size_t)row * N + col;
        if (Cb) Cb[idx] = f2bf(v); else Cf[idx] = v;
      }
    }
}

// ---- MFMA attention -------------------------------------------------------
// mode0: heads 4..7 local; qsrc=kvsrc=xqkv (stride 768; k +256, v +512); out bf16
// mode1: global all heads; qsrc=Qg (256), kvsrc=kv2 (512; k +0, v +256); out f32
__global__ __launch_bounds__(256) void msa_attn_mfma_r11(
    const unsigned short* __restrict__ qsrc, const unsigned short* __restrict__ kvsrc,
    float* __restrict__ outf, unsigned short* __restrict__ outb, int mode)
{
  __shared__ __align__(16) unsigned short K_lds[32][40];
  __shared__ __align__(16) unsigned short V_lds[32][40];
  __shared__ __align__(16) unsigned short P_lds[4][16][40];

  const int tid = threadIdx.x;
  const int wave = tid >> 6, lane = tid & 63;
  const int q16 = lane & 15, h = lane >> 4;
  const int b = blockIdx.y;

  int head, NTOK, P2, lp, pm1, base, qstr, kvstr, kofs, vofs;
  if (mode) {
    head = blockIdx.z; NTOK = 1024; P2 = 1024; lp = 0; pm1 = 0; base = 0;
    qstr = 256; kvstr = 512; kofs = 0; vofs = 256;
  } else {
    head = 4 + blockIdx.z;
    lp = (head < 6) ? 4 : 5;
    const int p = 1 << lp; pm1 = p - 1;
    NTOK = 4096; P2 = p * p;
    const int patch = (blockIdx.x * 64) >> (2 * lp);
    const int nbp = 64 >> lp;
    const int hb = patch / nbp, wb = patch - (patch / nbp) * nbp;
    base = ((hb << lp)) * 64 + (wb << lp);
    qstr = 768; kvstr = 768; kofs = 256; vofs = 512;
  }
  const int nq = blockIdx.x * 64 + wave * 16 + q16;
  int n;
  if (mode) n = nq;
  else { const int t = nq & (P2 - 1); n = base + ((t >> lp) << 6) + (t & pm1); }

  const bf16x8 qfrag = *reinterpret_cast<const bf16x8*>(
      qsrc + ((size_t)b * NTOK + n) * qstr + head * 32 + 8 * h);

  const float scale = 0.17677669529663687f;
  float m = -3.0e38f, l = 0.f;
  f32x4 o0 = {0.f, 0.f, 0.f, 0.f}, o1 = {0.f, 0.f, 0.f, 0.f};
  const f32x4 zc = {0.f, 0.f, 0.f, 0.f};

  const int skey = (tid & 127) >> 2;
  const int sh = tid & 3;
  const bool isK = tid < 128;

  for (int kc = 0; kc < P2; kc += 32) {
    __syncthreads();
    {
      const int kk = kc + skey;
      const int nk = mode ? kk : base + ((kk >> lp) << 6) + (kk & pm1);
      const unsigned short* src = kvsrc + ((size_t)b * NTOK + nk) * kvstr + head * 32
                                + (isK ? kofs : vofs) + 8 * sh;
      const bf16x8 v = *reinterpret_cast<const bf16x8*>(src);
      if (isK) {
        *reinterpret_cast<bf16x8*>(&K_lds[skey][8 * sh]) = v;
      } else {
#pragma unroll
        for (int j = 0; j < 8; ++j)
          V_lds[8 * sh + j][skey] = (unsigned short)v[j];
      }
    }
    __syncthreads();

    const bf16x8 k0 = *reinterpret_cast<const bf16x8*>(&K_lds[q16][8 * h]);
    const bf16x8 k1 = *reinterpret_cast<const bf16x8*>(&K_lds[16 + q16][8 * h]);
    const f32x4 st0 = __builtin_amdgcn_mfma_f32_16x16x32_bf16(k0, qfrag, zc, 0, 0, 0);
    const f32x4 st1 = __builtin_amdgcn_mfma_f32_16x16x32_bf16(k1, qfrag, zc, 0, 0, 0);

    float s[8];
#pragma unroll
    for (int i = 0; i < 4; ++i) { s[i] = st0[i] * scale; s[4 + i] = st1[i] * scale; }
    float cmax = s[0];
#pragma unroll
    for (int i = 1; i < 8; ++i) cmax = fmaxf(cmax, s[i]);
    cmax = fmaxf(cmax, __shfl_xor(cmax, 16));
    cmax = fmaxf(cmax, __shfl_xor(cmax, 32));
    const float mnew = fmaxf(m, cmax);
    const float f = __expf(m - mnew);
    float ps = 0.f;
    unsigned short pb[8];
#pragma unroll
    for (int i = 0; i < 8; ++i) {
      const float pe = __expf(s[i] - mnew);
      ps += pe;
      pb[i] = f2bf(pe);
    }
    l = l * f + ps;
    o0 *= f; o1 *= f;
    m = mnew;

    *reinterpret_cast<uint2*>(&P_lds[wave][q16][4 * h]) =
        make_uint2((unsigned)pb[0] | ((unsigned)pb[1] << 16),
                   (unsigned)pb[2] | ((unsigned)pb[3] << 16));
    *reinterpret_cast<uint2*>(&P_lds[wave][q16][16 + 4 * h]) =
        make_uint2((unsigned)pb[4] | ((unsigned)pb[5] << 16),
                   (unsigned)pb[6] | ((unsigned)pb[7] << 16));

    const bf16x8 pf = *reinterpret_cast<const bf16x8*>(&P_lds[wave][q16][8 * h]);
    const bf16x8 v0 = *reinterpret_cast<const bf16x8*>(&V_lds[q16][8 * h]);
    const bf16x8 v1 = *reinterpret_cast<const bf16x8*>(&V_lds[16 + q16][8 * h]);
    o0 = __builtin_amdgcn_mfma_f32_16x16x32_bf16(v0, pf, o0, 0, 0, 0);
    o1 = __builtin_amdgcn_mfma_f32_16x16x32_bf16(v1, pf, o1, 0, 0, 0);
  }

  l = l + __shfl_xor(l, 16);
  l = l + __shfl_xor(l, 32);
  const float inv = 1.f / l;
  const size_t obase = ((size_t)b * NTOK + nq) * 256 + head * 32;
  if (mode) {
    float* dst = outf + obase;
    float4 w0, w1;
    w0.x = o0[0] * inv; w0.y = o0[1] * inv; w0.z = o0[2] * inv; w0.w = o0[3] * inv;
    w1.x = o1[0] * inv; w1.y = o1[1] * inv; w1.z = o1[2] * inv; w1.w = o1[3] * inv;
    *reinterpret_cast<float4*>(dst + 4 * h) = w0;
    *reinterpret_cast<float4*>(dst + 16 + 4 * h) = w1;
  } else {
    unsigned short* dst = outb + obase;
    uint2 w0, w1;
    w0.x = (unsigned)f2bf(o0[0] * inv) | ((unsigned)f2bf(o0[1] * inv) << 16);
    w0.y = (unsigned)f2bf(o0[2] * inv) | ((unsigned)f2bf(o0[3] * inv) << 16);
    w1.x = (unsigned)f2bf(o1[0] * inv) | ((unsigned)f2bf(o1[1] * inv) << 16);
    w1.y = (unsigned)f2bf(o1[2] * inv) | ((unsigned)f2bf(o1[3] * inv) << 16);
    *reinterpret_cast<uint2*>(dst + 4 * h) = w0;
    *reinterpret_cast<uint2*>(dst + 16 + 4 * h) = w1;
  }
}

// ---- small heads (p=4,8): fp32 register path over xqkv --------------------
__global__ __launch_bounds__(64) void msa_attn_small_r11(
    const unsigned short* __restrict__ xqkv, unsigned short* __restrict__ out)
{
  const int head = blockIdx.z;
  const int p = (head < 2) ? 4 : 8;
  const int b = blockIdx.y;
  const int nq = blockIdx.x * 64 + threadIdx.x;
  const int P2 = p * p;
  const int patch = nq / P2;
  const int t = nq - patch * P2;
  const int nbp = 64 / p;
  const int hb = patch / nbp, wb = patch - (patch / nbp) * nbp;
  const int n = (hb * p + t / p) * 64 + (wb * p + t - (t / p) * p);

  float qr[32];
  {
    const bf16x8* q8 = reinterpret_cast<const bf16x8*>(
        xqkv + ((size_t)b * 4096 + n) * 768 + head * 32);
#pragma unroll
    for (int i = 0; i < 4; ++i) {
      const bf16x8 v = q8[i];
#pragma unroll
      for (int j = 0; j < 8; ++j) qr[i * 8 + j] = bf2f((unsigned short)v[j]);
    }
  }
  const float scale = 0.17677669529663687f;
  float m = -3.0e38f, l = 0.f;
  float acc[32] = {};
  const int kbase = (hb * p) * 64 + wb * p;
  for (int kk = 0; kk < P2; ++kk) {
    const int nk = kbase + (kk / p) * 64 + (kk - (kk / p) * p);
    const unsigned short* rowp = xqkv + ((size_t)b * 4096 + nk) * 768 + head * 32;
    const bf16x8* k8p = reinterpret_cast<const bf16x8*>(rowp + 256);
    const bf16x8* v8p = reinterpret_cast<const bf16x8*>(rowp + 512);
    float s = 0.f;
#pragma unroll
    for (int i = 0; i < 4; ++i) {
      const bf16x8 k8 = k8p[i];
#pragma unroll
      for (int j = 0; j < 8; ++j) s = fmaf(qr[i * 8 + j], bf2f((unsigned short)k8[j]), s);
    }
    s *= scale;
    if (s <= m) {
      const float pe = __expf(s - m);
      l += pe;
#pragma unroll
      for (int i = 0; i < 4; ++i) {
        const bf16x8 v8 = v8p[i];
#pragma unroll
        for (int j = 0; j < 8; ++j)
          acc[i * 8 + j] = fmaf(pe, bf2f((unsigned short)v8[j]), acc[i * 8 + j]);
      }
    } else {
      const float f = __expf(m - s);
      l = fmaf(l, f, 1.f);
#pragma unroll
      for (int i = 0; i < 4; ++i) {
        const bf16x8 v8 = v8p[i];
#pragma unroll
        for (int j = 0; j < 8; ++j)
          acc[i * 8 + j] = fmaf(acc[i * 8 + j], f, bf2f((unsigned short)v8[j]));
      }
      m = s;
    }
  }
  const float inv = 1.f / l;
  unsigned short* dst = out + ((size_t)b * 4096 + nq) * 256 + head * 32;
#pragma unroll
  for (int c = 0; c < 32; ++c) dst[c] = f2bf(acc[c] * inv);
}

// ---- qg_reduce: R-way parallel patch-mean ---------------------------------
// qg_all[b][head][t][c] = mean over nbp^2 patches; R=8 for p<=8, R=1 for p>=16.
// thread slot within head: gid = ((t*R + r)*32 + c); c fastest -> coalesced.
__global__ __launch_bounds__(256) void msa_qg_reduce_r11(
    const unsigned short* __restrict__ xqkv, float* __restrict__ qg_all)
{
  __shared__ float red[256];
  const int head = blockIdx.z;
  const int lp = (head < 2) ? 2 : (head < 4) ? 3 : (head < 6) ? 4 : 5;
  const int p = 1 << lp;
  const int P2 = p * p;
  const int nbp = 64 >> lp;
  const int npat = nbp * nbp;
  const int R = (lp <= 3) ? 8 : 1;
  const int total = P2 * 32 * R;
  const int gid = blockIdx.x * 256 + threadIdx.x;
  if (gid >= total) return;            // whole blocks exit (total % 256 == 0)
  const int b = blockIdx.y;

  const int c = gid & 31;
  const int tr = gid >> 5;
  const int r = tr & (R - 1);
  const int t = tr >> ((R == 8) ? 3 : 0);
  const int hp = t >> lp, wp = t & (p - 1);

  const unsigned short* src = xqkv + (size_t)b * 4096 * 768 + head * 32 + c;
  float s = 0.f;
  for (int j = r; j < npat; j += R) {
    const int hb = j / nbp, wb = j - (j / nbp) * nbp;
    const int n = ((hb << lp) + hp) * 64 + (wb << lp) + wp;
    s += bf2f(src[(size_t)n * 768]);
  }

  if (R == 8) {
    red[threadIdx.x] = s;
    __syncthreads();
    if (r < 4) red[threadIdx.x] += red[threadIdx.x + 128];
    __syncthreads();
    if (r < 2) red[threadIdx.x] += red[threadIdx.x + 64];
    __syncthreads();
    if (r == 0) {
      s = red[threadIdx.x] + red[threadIdx.x + 32];
      qg_all[((size_t)b * 8 + head) * 32768 + (size_t)t * 32 + c] = s / (float)npat;
    }
  } else {
    qg_all[((size_t)b * 8 + head) * 32768 + (size_t)t * 32 + c] = s / (float)npat;
  }
}

// ---- bilinear upsample (p x p -> 32 x 32) -> Qg bf16 ----------------------
__global__ __launch_bounds__(256) void msa_qg_upsample_r11(
    const float* __restrict__ qg_all, unsigned short* __restrict__ Qg)
{
  const int head = blockIdx.z;
  const int p = (head < 2) ? 4 : (head < 4) ? 8 : (head < 6) ? 16 : 32;
  const int e = blockIdx.x * 256 + threadIdx.x;
  const int b = blockIdx.y;
  const int mlin = e >> 5, c = e & 31;
  const int mi = mlin >> 5, mj = mlin & 31;
  const float* src = qg_all + ((size_t)b * 8 + head) * 32768;
  float v;
  if (p == 32) {
    v = src[(size_t)mlin * 32 + c];
  } else {
    const float s = (float)p / 32.0f;
    const float xf = (mj + 0.5f) * s - 0.5f;
    const float yf = (mi + 0.5f) * s - 0.5f;
    const float xfl = floorf(xf), yfl = floorf(yf);
    const float fx = xf - xfl, fy = yf - yfl;
    const int x0 = (int)xfl, y0 = (int)yfl;
    const int x0c = max(0, min(p - 1, x0)), x1c = max(0, min(p - 1, x0 + 1));
    const int y0c = max(0, min(p - 1, y0)), y1c = max(0, min(p - 1, y0 + 1));
    const float v00 = src[(size_t)(y0c * p + x0c) * 32 + c];
    const float v01 = src[(size_t)(y0c * p + x1c) * 32 + c];
    const float v10 = src[(size_t)(y1c * p + x0c) * 32 + c];
    const float v11 = src[(size_t)(y1c * p + x1c) * 32 + c];
    v = (1.f - fy) * ((1.f - fx) * v00 + fx * v01)
      + fy * ((1.f - fx) * v10 + fx * v11);
  }
  Qg[((size_t)b * 1024 + mlin) * 256 + head * 32 + c] = f2bf(v);
}

// ---- 2x2 avg pool over the n'-grid -> pooled [B,1024,256] bf16 ------------
__global__ __launch_bounds__(256) void msa_pool_r11(
    const unsigned short* __restrict__ attn, unsigned short* __restrict__ pooled)
{
  const int c = threadIdx.x;
  const int mlin = blockIdx.x;
  const int b = blockIdx.y;
  const int mi = mlin >> 5, mj = mlin & 31;
  const size_t base = (size_t)b * 4096;
  const int r0 = mi * 2, q0 = mj * 2;
  float s = bf2f(attn[(base + (r0 * 64 + q0)) * 256 + c])
          + bf2f(attn[(base + (r0 * 64 + q0 + 1)) * 256 + c])
          + bf2f(attn[(base + ((r0 + 1) * 64 + q0)) * 256 + c])
          + bf2f(attn[(base + ((r0 + 1) * 64 + q0 + 1)) * 256 + c]);
  pooled[((size_t)b * 1024 + mlin) * 256 + c] = f2bf(s * 0.25f);
}

// ---- blend: attn[n] = bf16( attn[n] + upsample(gl)[n] ) -------------------
__global__ __launch_bounds__(256) void msa_blend_r11(
    const float* __restrict__ gl, unsigned short* __restrict__ attn)
{
  const int c = threadIdx.x;
  const int n = blockIdx.x;
  const int b = blockIdx.y;
  const int hh = n >> 6, w = n & 63;
  const float xf = (w + 0.5f) * 0.5f - 0.5f;
  const float yf = (hh + 0.5f) * 0.5f - 0.5f;
  const float xfl = floorf(xf), yfl = floorf(yf);
  const float fx = xf - xfl, fy = yf - yfl;
  const int x0 = (int)xfl, y0 = (int)yfl;
  const int x0c = max(0, min(31, x0)), x1c = max(0, min(31, x0 + 1));
  const int y0c = max(0, min(31, y0)), y1c = max(0, min(31, y0 + 1));
  const float* g = gl + (size_t)b * 1024 * 256;
  const float v00 = g[(size_t)(y0c * 32 + x0c) * 256 + c];
  const float v01 = g[(size_t)(y0c * 32 + x1c) * 256 + c];
  const float v10 = g[(size_t)(y1c * 32 + x0c) * 256 + c];
  const float v11 = g[(size_t)(y1c * 32 + x1c) * 256 + c];
  const float v = (1.f - fy) * ((1.f - fx) * v00 + fx * v01)
                + fy * ((1.f - fx) * v10 + fx * v11);
  const size_t idx = ((size_t)b * 4096 + n) * 256 + c;
  attn[idx] = f2bf(bf2f(attn[idx]) + v);
}

extern "C" void kernel_launch(void* const* d_in, const int* in_sizes, int n_in,
                              void* d_out, int out_size, void* d_ws, size_t ws_size,
                              hipStream_t stream)
{
  const float* x     = (const float*)d_in[0];
  const float* Wq    = (const float*)d_in[1];
  const float* Wkv   = (const float*)d_in[2];
  const float* Wlkv  = (const float*)d_in[3];
  const float* Wproj = (const float*)d_in[4];
  const float* bproj = (const float*)d_in[5];

  char* ws = (char*)d_ws;
  unsigned short* xqkv  = (unsigned short*)(ws + 0);            // [32768,768] bf16
  unsigned short* attnb = (unsigned short*)(ws + 50331648ull);  // [32768,256] bf16
  unsigned short* Qg    = (unsigned short*)(ws + 67108864ull);  // [8192,256] bf16
  float* qg_all = (float*)(ws + 71303168ull);                   // [8,8,1024,32] f32
  unsigned short* Wqkvt = (unsigned short*)(ws + 79691776ull);  // [768,256] bf16
  unsigned short* Wlkvt = (unsigned short*)(ws + 80084992ull);  // [512,256] bf16
  unsigned short* Wprjt = (unsigned short*)(ws + 80347136ull);  // [256,256] bf16
  float* gl     = (float*)(ws + 80478208ull);                   // [8192,256] f32
  unsigned short* pooled = (unsigned short*)(ws + 0);           // over dead xqkv
  unsigned short* kv2    = (unsigned short*)(ws + 16777216ull); // over dead xqkv

  // 0) fused weight casts
  msa_wcast_r11<<<dim3(1536), 256, 0, stream>>>(Wq, Wkv, Wlkv, Wproj, Wqkvt, Wlkvt, Wprjt);

  // 1) fused QKV projection (MFMA, bf16 store): xqkv = x @ [Wq|Wkv]
  msa_gemm_mfma_r11<<<dim3(6, 256), 256, 0, stream>>>(x, nullptr, Wqkvt, nullptr, nullptr, xqkv, 256, 768);

  // 2) global-query means + bilinear upsample
  msa_qg_reduce_r11<<<dim3(128, 8, 8), 256, 0, stream>>>(xqkv, qg_all);
  msa_qg_upsample_r11<<<dim3(128, 8, 8), 256, 0, stream>>>(qg_all, Qg);

  // 3) local windowed attention (bf16 out)
  msa_attn_small_r11<<<dim3(64, 8, 4), 64, 0, stream>>>(xqkv, attnb);
  msa_attn_mfma_r11<<<dim3(64, 8, 4), 256, 0, stream>>>(xqkv, xqkv, nullptr, attnb, 0);

  // 4) pool + kv2 projection (MFMA)
  msa_pool_r11<<<dim3(1024, 8), 256, 0, stream>>>(attnb, pooled);
  msa_gemm_mfma_r11<<<dim3(4, 64), 256, 0, stream>>>(nullptr, pooled, Wlkvt, nullptr, nullptr, kv2, 256, 512);

  // 5) global cross-attention (f32 out to gl)
  msa_attn_mfma_r11<<<dim3(16, 8, 8), 256, 0, stream>>>(Qg, kv2, gl, nullptr, 1);

  // 6) blend + final projection (MFMA, fp32 out + bias)
  msa_blend_r11<<<dim3(4096, 8), 256, 0, stream>>>(gl, attnb);
  msa_gemm_mfma_r11<<<dim3(2, 256), 256, 0, stream>>>(nullptr, attnb, Wprjt, bproj, (float*)d_out, nullptr, 256, 256);

  (void)in_sizes; (void)n_in; (void)out_size; (void)ws_size;
}

// Round 12
// 235.234 us; speedup vs baseline: 51.0011x; 1.1998x over previous
//
#include <hip/hip_runtime.h>
#include <math.h>

// ---------------------------------------------------------------------------
// ROUND 12:
//  - p=8 heads moved to the MFMA attention kernel (lp=3: block==patch, valid)
//  - scalar small-head path now p=4 only, 256-thread blocks
//  - x pre-cast to bf16 once; QKV GEMM reads bf16 A (halves its HBM traffic)
// ---------------------------------------------------------------------------

typedef __attribute__((ext_vector_type(8))) short bf16x8;
typedef __attribute__((ext_vector_type(4))) float f32x4;

__device__ inline float bf2f(unsigned short u) {
  union { unsigned int i; float f; } v; v.i = ((unsigned int)u) << 16; return v.f;
}
__device__ inline unsigned short f2bf(float x) {
  union { float f; unsigned int i; } v; v.f = x;
  return (unsigned short)((v.i + 0x7FFFu + ((v.i >> 16) & 1u)) >> 16);
}

// ---- x cast: fp32 -> bf16, vectorized -------------------------------------
__global__ __launch_bounds__(256) void msa_xcast_r12(
    const float* __restrict__ x, unsigned short* __restrict__ xb)
{
  const size_t i = ((size_t)blockIdx.x * 256 + threadIdx.x) * 8;
  const float4 v0 = *reinterpret_cast<const float4*>(&x[i]);
  const float4 v1 = *reinterpret_cast<const float4*>(&x[i + 4]);
  bf16x8 o;
  o[0] = (short)f2bf(v0.x); o[1] = (short)f2bf(v0.y);
  o[2] = (short)f2bf(v0.z); o[3] = (short)f2bf(v0.w);
  o[4] = (short)f2bf(v1.x); o[5] = (short)f2bf(v1.y);
  o[6] = (short)f2bf(v1.z); o[7] = (short)f2bf(v1.w);
  *reinterpret_cast<bf16x8*>(&xb[i]) = o;
}

// ---- fused weight cast+transpose ------------------------------------------
__global__ __launch_bounds__(256) void msa_wcast_r12(
    const float* __restrict__ Wq, const float* __restrict__ Wkv,
    const float* __restrict__ Wlkv, const float* __restrict__ Wproj,
    unsigned short* __restrict__ Wqkvt, unsigned short* __restrict__ Wlkvt,
    unsigned short* __restrict__ Wprjt)
{
  const int id = blockIdx.x * 256 + threadIdx.x;
  if (id < 196608) {
    const int r = id >> 8, k = id & 255;
    const float v = (r < 256) ? Wq[(size_t)k * 256 + r] : Wkv[(size_t)k * 512 + (r - 256)];
    Wqkvt[id] = f2bf(v);
  } else if (id < 327680) {
    const int j = id - 196608;
    const int n = j >> 8, k = j & 255;
    Wlkvt[j] = f2bf(Wlkv[(size_t)k * 512 + n]);
  } else if (id < 393216) {
    const int j = id - 327680;
    const int n = j >> 8, k = j & 255;
    Wprjt[j] = f2bf(Wproj[(size_t)k * 256 + n]);
  }
}

// ---- MFMA GEMM: C[M,N] = A[M,256] @ W[256,N] (+bias), A bf16 --------------
__global__ __launch_bounds__(256) void msa_gemm_mfma_r12(
    const unsigned short* __restrict__ Ab, const unsigned short* __restrict__ Wt,
    const float* __restrict__ bias, float* __restrict__ Cf,
    unsigned short* __restrict__ Cb, int K, int N)
{
  __shared__ __align__(16) unsigned short A_lds[128][40];
  __shared__ __align__(16) unsigned short B_lds[128][40];

  const int tid = threadIdx.x;
  const int wave = tid >> 6, lane = tid & 63;
  const int l15 = lane & 15, g = lane >> 4;
  const int bm = blockIdx.y * 128, bn = blockIdx.x * 128;
  const int wr = (wave >> 1) * 64, wc = (wave & 1) * 64;

  f32x4 acc[4][4] = {};

  for (int k0 = 0; k0 < K; k0 += 32) {
    __syncthreads();
#pragma unroll
    for (int s = 0; s < 2; ++s) {
      const int id = tid + s * 256;
      const int row = id >> 2, sg = (id & 3) << 3;
      *reinterpret_cast<bf16x8*>(&A_lds[row][sg]) =
          *reinterpret_cast<const bf16x8*>(&Ab[(size_t)(bm + row) * K + k0 + sg]);
      *reinterpret_cast<bf16x8*>(&B_lds[row][sg]) =
          *reinterpret_cast<const bf16x8*>(&Wt[(size_t)(bn + row) * K + k0 + sg]);
    }
    __syncthreads();

    bf16x8 a_frag[4], b_frag[4];
#pragma unroll
    for (int mi = 0; mi < 4; ++mi)
      a_frag[mi] = *reinterpret_cast<const bf16x8*>(&A_lds[wr + mi * 16 + l15][g << 3]);
#pragma unroll
    for (int ni = 0; ni < 4; ++ni)
      b_frag[ni] = *reinterpret_cast<const bf16x8*>(&B_lds[wc + ni * 16 + l15][g << 3]);
#pragma unroll
    for (int mi = 0; mi < 4; ++mi)
#pragma unroll
      for (int ni = 0; ni < 4; ++ni)
        acc[mi][ni] = __builtin_amdgcn_mfma_f32_16x16x32_bf16(
            a_frag[mi], b_frag[ni], acc[mi][ni], 0, 0, 0);
  }

#pragma unroll
  for (int mi = 0; mi < 4; ++mi)
#pragma unroll
    for (int ni = 0; ni < 4; ++ni) {
      const int col = bn + wc + ni * 16 + l15;
#pragma unroll
      for (int i = 0; i < 4; ++i) {
        const int row = bm + wr + mi * 16 + g * 4 + i;
        float v = acc[mi][ni][i];
        if (bias) v += bias[col];
        const size_t idx = (size_t)row * N + col;
        if (Cb) Cb[idx] = f2bf(v); else Cf[idx] = v;
      }
    }
}

// ---- MFMA attention -------------------------------------------------------
// mode0: heads 2..7 local (z: head=2+z, lp=3/4/5); xqkv stride 768, k+256,v+512
// mode1: global all heads; qsrc=Qg (256), kvsrc=kv2 (512; k+0,v+256); out f32
__global__ __launch_bounds__(256) void msa_attn_mfma_r12(
    const unsigned short* __restrict__ qsrc, const unsigned short* __restrict__ kvsrc,
    float* __restrict__ outf, unsigned short* __restrict__ outb, int mode)
{
  __shared__ __align__(16) unsigned short K_lds[32][40];
  __shared__ __align__(16) unsigned short V_lds[32][40];
  __shared__ __align__(16) unsigned short P_lds[4][16][40];

  const int tid = threadIdx.x;
  const int wave = tid >> 6, lane = tid & 63;
  const int q16 = lane & 15, h = lane >> 4;
  const int b = blockIdx.y;

  int head, NTOK, P2, lp, pm1, base, qstr, kvstr, kofs, vofs;
  if (mode) {
    head = blockIdx.z; NTOK = 1024; P2 = 1024; lp = 0; pm1 = 0; base = 0;
    qstr = 256; kvstr = 512; kofs = 0; vofs = 256;
  } else {
    head = 2 + blockIdx.z;
    lp = (head < 4) ? 3 : (head < 6) ? 4 : 5;
    const int p = 1 << lp; pm1 = p - 1;
    NTOK = 4096; P2 = p * p;
    const int patch = (blockIdx.x * 64) >> (2 * lp);
    const int nbp = 64 >> lp;
    const int hb = patch / nbp, wb = patch - (patch / nbp) * nbp;
    base = ((hb << lp)) * 64 + (wb << lp);
    qstr = 768; kvstr = 768; kofs = 256; vofs = 512;
  }
  const int nq = blockIdx.x * 64 + wave * 16 + q16;
  int n;
  if (mode) n = nq;
  else { const int t = nq & (P2 - 1); n = base + ((t >> lp) << 6) + (t & pm1); }

  const bf16x8 qfrag = *reinterpret_cast<const bf16x8*>(
      qsrc + ((size_t)b * NTOK + n) * qstr + head * 32 + 8 * h);

  const float scale = 0.17677669529663687f;
  float m = -3.0e38f, l = 0.f;
  f32x4 o0 = {0.f, 0.f, 0.f, 0.f}, o1 = {0.f, 0.f, 0.f, 0.f};
  const f32x4 zc = {0.f, 0.f, 0.f, 0.f};

  const int skey = (tid & 127) >> 2;
  const int sh = tid & 3;
  const bool isK = tid < 128;

  for (int kc = 0; kc < P2; kc += 32) {
    __syncthreads();
    {
      const int kk = kc + skey;
      const int nk = mode ? kk : base + ((kk >> lp) << 6) + (kk & pm1);
      const unsigned short* src = kvsrc + ((size_t)b * NTOK + nk) * kvstr + head * 32
                                + (isK ? kofs : vofs) + 8 * sh;
      const bf16x8 v = *reinterpret_cast<const bf16x8*>(src);
      if (isK) {
        *reinterpret_cast<bf16x8*>(&K_lds[skey][8 * sh]) = v;
      } else {
#pragma unroll
        for (int j = 0; j < 8; ++j)
          V_lds[8 * sh + j][skey] = (unsigned short)v[j];
      }
    }
    __syncthreads();

    const bf16x8 k0 = *reinterpret_cast<const bf16x8*>(&K_lds[q16][8 * h]);
    const bf16x8 k1 = *reinterpret_cast<const bf16x8*>(&K_lds[16 + q16][8 * h]);
    const f32x4 st0 = __builtin_amdgcn_mfma_f32_16x16x32_bf16(k0, qfrag, zc, 0, 0, 0);
    const f32x4 st1 = __builtin_amdgcn_mfma_f32_16x16x32_bf16(k1, qfrag, zc, 0, 0, 0);

    float s[8];
#pragma unroll
    for (int i = 0; i < 4; ++i) { s[i] = st0[i] * scale; s[4 + i] = st1[i] * scale; }
    float cmax = s[0];
#pragma unroll
    for (int i = 1; i < 8; ++i) cmax = fmaxf(cmax, s[i]);
    cmax = fmaxf(cmax, __shfl_xor(cmax, 16));
    cmax = fmaxf(cmax, __shfl_xor(cmax, 32));
    const float mnew = fmaxf(m, cmax);
    const float f = __expf(m - mnew);
    float ps = 0.f;
    unsigned short pb[8];
#pragma unroll
    for (int i = 0; i < 8; ++i) {
      const float pe = __expf(s[i] - mnew);
      ps += pe;
      pb[i] = f2bf(pe);
    }
    l = l * f + ps;
    o0 *= f; o1 *= f;
    m = mnew;

    *reinterpret_cast<uint2*>(&P_lds[wave][q16][4 * h]) =
        make_uint2((unsigned)pb[0] | ((unsigned)pb[1] << 16),
                   (unsigned)pb[2] | ((unsigned)pb[3] << 16));
    *reinterpret_cast<uint2*>(&P_lds[wave][q16][16 + 4 * h]) =
        make_uint2((unsigned)pb[4] | ((unsigned)pb[5] << 16),
                   (unsigned)pb[6] | ((unsigned)pb[7] << 16));

    const bf16x8 pf = *reinterpret_cast<const bf16x8*>(&P_lds[wave][q16][8 * h]);
    const bf16x8 v0 = *reinterpret_cast<const bf16x8*>(&V_lds[q16][8 * h]);
    const bf16x8 v1 = *reinterpret_cast<const bf16x8*>(&V_lds[16 + q16][8 * h]);
    o0 = __builtin_amdgcn_mfma_f32_16x16x32_bf16(v0, pf, o0, 0, 0, 0);
    o1 = __builtin_amdgcn_mfma_f32_16x16x32_bf16(v1, pf, o1, 0, 0, 0);
  }

  l = l + __shfl_xor(l, 16);
  l = l + __shfl_xor(l, 32);
  const float inv = 1.f / l;
  const size_t obase = ((size_t)b * NTOK + nq) * 256 + head * 32;
  if (mode) {
    float* dst = outf + obase;
    float4 w0, w1;
    w0.x = o0[0] * inv; w0.y = o0[1] * inv; w0.z = o0[2] * inv; w0.w = o0[3] * inv;
    w1.x = o1[0] * inv; w1.y = o1[1] * inv; w1.z = o1[2] * inv; w1.w = o1[3] * inv;
    *reinterpret_cast<float4*>(dst + 4 * h) = w0;
    *reinterpret_cast<float4*>(dst + 16 + 4 * h) = w1;
  } else {
    unsigned short* dst = outb + obase;
    uint2 w0, w1;
    w0.x = (unsigned)f2bf(o0[0] * inv) | ((unsigned)f2bf(o0[1] * inv) << 16);
    w0.y = (unsigned)f2bf(o0[2] * inv) | ((unsigned)f2bf(o0[3] * inv) << 16);
    w1.x = (unsigned)f2bf(o1[0] * inv) | ((unsigned)f2bf(o1[1] * inv) << 16);
    w1.y = (unsigned)f2bf(o1[2] * inv) | ((unsigned)f2bf(o1[3] * inv) << 16);
    *reinterpret_cast<uint2*>(dst + 4 * h) = w0;
    *reinterpret_cast<uint2*>(dst + 16 + 4 * h) = w1;
  }
}

// ---- p=4 heads only (heads 0,1): scalar path, 256-thread blocks -----------
__global__ __launch_bounds__(256) void msa_attn_p4_r12(
    const unsigned short* __restrict__ xqkv, unsigned short* __restrict__ out)
{
  const int head = blockIdx.z;               // 0 or 1
  const int b = blockIdx.y;
  const int nq = blockIdx.x * 256 + threadIdx.x;

  const int patch = nq >> 4;
  const int t = nq & 15;
  const int hb = patch >> 4, wb = patch & 15;
  const int n = (hb * 4 + (t >> 2)) * 64 + (wb * 4 + (t & 3));

  float qr[32];
  {
    const bf16x8* q8 = reinterpret_cast<const bf16x8*>(
        xqkv + ((size_t)b * 4096 + n) * 768 + head * 32);
#pragma unroll
    for (int i = 0; i < 4; ++i) {
      const bf16x8 v = q8[i];
#pragma unroll
      for (int j = 0; j < 8; ++j) qr[i * 8 + j] = bf2f((unsigned short)v[j]);
    }
  }
  const float scale = 0.17677669529663687f;
  float m = -3.0e38f, l = 0.f;
  float acc[32] = {};
  const int kbase = (hb * 4) * 64 + wb * 4;
  for (int kk = 0; kk < 16; ++kk) {
    const int nk = kbase + (kk >> 2) * 64 + (kk & 3);
    const unsigned short* rowp = xqkv + ((size_t)b * 4096 + nk) * 768 + head * 32;
    const bf16x8* k8p = reinterpret_cast<const bf16x8*>(rowp + 256);
    const bf16x8* v8p = reinterpret_cast<const bf16x8*>(rowp + 512);
    float s = 0.f;
#pragma unroll
    for (int i = 0; i < 4; ++i) {
      const bf16x8 k8 = k8p[i];
#pragma unroll
      for (int j = 0; j < 8; ++j) s = fmaf(qr[i * 8 + j], bf2f((unsigned short)k8[j]), s);
    }
    s *= scale;
    if (s <= m) {
      const float pe = __expf(s - m);
      l += pe;
#pragma unroll
      for (int i = 0; i < 4; ++i) {
        const bf16x8 v8 = v8p[i];
#pragma unroll
        for (int j = 0; j < 8; ++j)
          acc[i * 8 + j] = fmaf(pe, bf2f((unsigned short)v8[j]), acc[i * 8 + j]);
      }
    } else {
      const float f = __expf(m - s);
      l = fmaf(l, f, 1.f);
#pragma unroll
      for (int i = 0; i < 4; ++i) {
        const bf16x8 v8 = v8p[i];
#pragma unroll
        for (int j = 0; j < 8; ++j)
          acc[i * 8 + j] = fmaf(acc[i * 8 + j], f, bf2f((unsigned short)v8[j]));
      }
      m = s;
    }
  }
  const float inv = 1.f / l;
  unsigned short* dst = out + ((size_t)b * 4096 + nq) * 256 + head * 32;
#pragma unroll
  for (int c = 0; c < 32; ++c) dst[c] = f2bf(acc[c] * inv);
}

// ---- qg_reduce: R-way parallel patch-mean ---------------------------------
__global__ __launch_bounds__(256) void msa_qg_reduce_r12(
    const unsigned short* __restrict__ xqkv, float* __restrict__ qg_all)
{
  __shared__ float red[256];
  const int head = blockIdx.z;
  const int lp = (head < 2) ? 2 : (head < 4) ? 3 : (head < 6) ? 4 : 5;
  const int p = 1 << lp;
  const int P2 = p * p;
  const int nbp = 64 >> lp;
  const int npat = nbp * nbp;
  const int R = (lp <= 3) ? 8 : 1;
  const int total = P2 * 32 * R;
  const int gid = blockIdx.x * 256 + threadIdx.x;
  if (gid >= total) return;
  const int b = blockIdx.y;

  const int c = gid & 31;
  const int tr = gid >> 5;
  const int r = tr & (R - 1);
  const int t = tr >> ((R == 8) ? 3 : 0);
  const int hp = t >> lp, wp = t & (p - 1);

  const unsigned short* src = xqkv + (size_t)b * 4096 * 768 + head * 32 + c;
  float s = 0.f;
  for (int j = r; j < npat; j += R) {
    const int hb = j / nbp, wb = j - (j / nbp) * nbp;
    const int n = ((hb << lp) + hp) * 64 + (wb << lp) + wp;
    s += bf2f(src[(size_t)n * 768]);
  }

  if (R == 8) {
    red[threadIdx.x] = s;
    __syncthreads();
    if (r < 4) red[threadIdx.x] += red[threadIdx.x + 128];
    __syncthreads();
    if (r < 2) red[threadIdx.x] += red[threadIdx.x + 64];
    __syncthreads();
    if (r == 0) {
      s = red[threadIdx.x] + red[threadIdx.x + 32];
      qg_all[((size_t)b * 8 + head) * 32768 + (size_t)t * 32 + c] = s / (float)npat;
    }
  } else {
    qg_all[((size_t)b * 8 + head) * 32768 + (size_t)t * 32 + c] = s / (float)npat;
  }
}

// ---- bilinear upsample (p x p -> 32 x 32) -> Qg bf16 ----------------------
__global__ __launch_bounds__(256) void msa_qg_upsample_r12(
    const float* __restrict__ qg_all, unsigned short* __restrict__ Qg)
{
  const int head = blockIdx.z;
  const int p = (head < 2) ? 4 : (head < 4) ? 8 : (head < 6) ? 16 : 32;
  const int e = blockIdx.x * 256 + threadIdx.x;
  const int b = blockIdx.y;
  const int mlin = e >> 5, c = e & 31;
  const int mi = mlin >> 5, mj = mlin & 31;
  const float* src = qg_all + ((size_t)b * 8 + head) * 32768;
  float v;
  if (p == 32) {
    v = src[(size_t)mlin * 32 + c];
  } else {
    const float s = (float)p / 32.0f;
    const float xf = (mj + 0.5f) * s - 0.5f;
    const float yf = (mi + 0.5f) * s - 0.5f;
    const float xfl = floorf(xf), yfl = floorf(yf);
    const float fx = xf - xfl, fy = yf - yfl;
    const int x0 = (int)xfl, y0 = (int)yfl;
    const int x0c = max(0, min(p - 1, x0)), x1c = max(0, min(p - 1, x0 + 1));
    const int y0c = max(0, min(p - 1, y0)), y1c = max(0, min(p - 1, y0 + 1));
    const float v00 = src[(size_t)(y0c * p + x0c) * 32 + c];
    const float v01 = src[(size_t)(y0c * p + x1c) * 32 + c];
    const float v10 = src[(size_t)(y1c * p + x0c) * 32 + c];
    const float v11 = src[(size_t)(y1c * p + x1c) * 32 + c];
    v = (1.f - fy) * ((1.f - fx) * v00 + fx * v01)
      + fy * ((1.f - fx) * v10 + fx * v11);
  }
  Qg[((size_t)b * 1024 + mlin) * 256 + head * 32 + c] = f2bf(v);
}

// ---- 2x2 avg pool -> pooled [B,1024,256] bf16 -----------------------------
__global__ __launch_bounds__(256) void msa_pool_r12(
    const unsigned short* __restrict__ attn, unsigned short* __restrict__ pooled)
{
  const int c = threadIdx.x;
  const int mlin = blockIdx.x;
  const int b = blockIdx.y;
  const int mi = mlin >> 5, mj = mlin & 31;
  const size_t base = (size_t)b * 4096;
  const int r0 = mi * 2, q0 = mj * 2;
  float s = bf2f(attn[(base + (r0 * 64 + q0)) * 256 + c])
          + bf2f(attn[(base + (r0 * 64 + q0 + 1)) * 256 + c])
          + bf2f(attn[(base + ((r0 + 1) * 64 + q0)) * 256 + c])
          + bf2f(attn[(base + ((r0 + 1) * 64 + q0 + 1)) * 256 + c]);
  pooled[((size_t)b * 1024 + mlin) * 256 + c] = f2bf(s * 0.25f);
}

// ---- blend: attn[n] = bf16( attn[n] + upsample(gl)[n] ) -------------------
__global__ __launch_bounds__(256) void msa_blend_r12(
    const float* __restrict__ gl, unsigned short* __restrict__ attn)
{
  const int c = threadIdx.x;
  const int n = blockIdx.x;
  const int b = blockIdx.y;
  const int hh = n >> 6, w = n & 63;
  const float xf = (w + 0.5f) * 0.5f - 0.5f;
  const float yf = (hh + 0.5f) * 0.5f - 0.5f;
  const float xfl = floorf(xf), yfl = floorf(yf);
  const float fx = xf - xfl, fy = yf - yfl;
  const int x0 = (int)xfl, y0 = (int)yfl;
  const int x0c = max(0, min(31, x0)), x1c = max(0, min(31, x0 + 1));
  const int y0c = max(0, min(31, y0)), y1c = max(0, min(31, y0 + 1));
  const float* g = gl + (size_t)b * 1024 * 256;
  const float v00 = g[(size_t)(y0c * 32 + x0c) * 256 + c];
  const float v01 = g[(size_t)(y0c * 32 + x1c) * 256 + c];
  const float v10 = g[(size_t)(y1c * 32 + x0c) * 256 + c];
  const float v11 = g[(size_t)(y1c * 32 + x1c) * 256 + c];
  const float v = (1.f - fy) * ((1.f - fx) * v00 + fx * v01)
                + fy * ((1.f - fx) * v10 + fx * v11);
  const size_t idx = ((size_t)b * 4096 + n) * 256 + c;
  attn[idx] = f2bf(bf2f(attn[idx]) + v);
}

extern "C" void kernel_launch(void* const* d_in, const int* in_sizes, int n_in,
                              void* d_out, int out_size, void* d_ws, size_t ws_size,
                              hipStream_t stream)
{
  const float* x     = (const float*)d_in[0];
  const float* Wq    = (const float*)d_in[1];
  const float* Wkv   = (const float*)d_in[2];
  const float* Wlkv  = (const float*)d_in[3];
  const float* Wproj = (const float*)d_in[4];
  const float* bproj = (const float*)d_in[5];

  char* ws = (char*)d_ws;
  unsigned short* xqkv  = (unsigned short*)(ws + 0);            // [32768,768] bf16
  unsigned short* attnb = (unsigned short*)(ws + 50331648ull);  // [32768,256] bf16
  unsigned short* Qg    = (unsigned short*)(ws + 67108864ull);  // [8192,256] bf16
  float* qg_all = (float*)(ws + 71303168ull);                   // [8,8,1024,32] f32
  unsigned short* Wqkvt = (unsigned short*)(ws + 79691776ull);  // [768,256] bf16
  unsigned short* Wlkvt = (unsigned short*)(ws + 80084992ull);  // [512,256] bf16
  unsigned short* Wprjt = (unsigned short*)(ws + 80347136ull);  // [256,256] bf16
  float* gl     = (float*)(ws + 80478208ull);                   // [8192,256] f32
  unsigned short* xb    = (unsigned short*)(ws + 88866816ull);  // [32768,256] bf16
  unsigned short* pooled = (unsigned short*)(ws + 0);           // over dead xqkv
  unsigned short* kv2    = (unsigned short*)(ws + 16777216ull); // over dead xqkv

  // 0) casts
  msa_xcast_r12<<<dim3(4096), 256, 0, stream>>>(x, xb);
  msa_wcast_r12<<<dim3(1536), 256, 0, stream>>>(Wq, Wkv, Wlkv, Wproj, Wqkvt, Wlkvt, Wprjt);

  // 1) fused QKV projection (MFMA, bf16 A): xqkv = xb @ [Wq|Wkv]
  msa_gemm_mfma_r12<<<dim3(6, 256), 256, 0, stream>>>(xb, Wqkvt, nullptr, nullptr, xqkv, 256, 768);

  // 2) global-query means + bilinear upsample
  msa_qg_reduce_r12<<<dim3(128, 8, 8), 256, 0, stream>>>(xqkv, qg_all);
  msa_qg_upsample_r12<<<dim3(128, 8, 8), 256, 0, stream>>>(qg_all, Qg);

  // 3) local windowed attention: p=4 scalar, p=8/16/32 MFMA
  msa_attn_p4_r12<<<dim3(16, 8, 2), 256, 0, stream>>>(xqkv, attnb);
  msa_attn_mfma_r12<<<dim3(64, 8, 6), 256, 0, stream>>>(xqkv, xqkv, nullptr, attnb, 0);

  // 4) pool + kv2 projection (MFMA)
  msa_pool_r12<<<dim3(1024, 8), 256, 0, stream>>>(attnb, pooled);
  msa_gemm_mfma_r12<<<dim3(4, 64), 256, 0, stream>>>(pooled, Wlkvt, nullptr, nullptr, kv2, 256, 512);

  // 5) global cross-attention (f32 out to gl)
  msa_attn_mfma_r12<<<dim3(16, 8, 8), 256, 0, stream>>>(Qg, kv2, gl, nullptr, 1);

  // 6) blend + final projection (MFMA, fp32 out + bias)
  msa_blend_r12<<<dim3(4096, 8), 256, 0, stream>>>(gl, attnb);
  msa_gemm_mfma_r12<<<dim3(2, 256), 256, 0, stream>>>(attnb, Wprjt, bproj, (float*)d_out, nullptr, 256, 256);

  (void)in_sizes; (void)n_in; (void)out_size; (void)ws_size;
}